// Round 6
// baseline (188.187 us; speedup 1.0000x reference)
//
#include <hip/hip_runtime.h>
#include <math.h>

#define DDIM 4096
#define NSEG 100
#define HDIM 128
#define BROWS 4096
#define TOPK 10
#define KSLICES 16

typedef __attribute__((ext_vector_type(8))) short bf16x8;
typedef __attribute__((ext_vector_type(4))) float f32x4;

// Branch-free gelu: A&S 7.1.26 erf (abs err <= 1.5e-7), v_exp_f32 + v_rcp_f32.
__device__ __forceinline__ float gelu_f(float x) {
    float u  = x * 0.70710678118654752440f;
    float au = fminf(fabsf(u), 3.9f);                 // erf(3.9) == 1 to fp32
    float t  = __builtin_amdgcn_rcpf(fmaf(0.3275911f, au, 1.0f));
    float p  = fmaf(fmaf(fmaf(fmaf(1.061405429f, t, -1.453152027f), t,
                              1.421413741f), t, -0.284496736f), t, 0.254829592f) * t;
    float e  = __expf(-au * au);
    float er = fmaf(-p, e, 1.0f);                     // erf(|u|)
    er = copysignf(er, u);
    return 0.5f * x * (1.0f + er);
}

// Split fp32 -> bf16 hi (truncate) + bf16 lo (exact residual, truncated).
__device__ __forceinline__ void split8(const float4& a, const float4& b,
                                       bf16x8& hi, bf16x8& lo) {
    float v[8] = {a.x, a.y, a.z, a.w, b.x, b.y, b.z, b.w};
    uint hw[4], lw[4];
    #pragma unroll
    for (int j = 0; j < 4; ++j) {
        uint u0 = __float_as_uint(v[2 * j]);
        uint u1 = __float_as_uint(v[2 * j + 1]);
        hw[j] = (u0 >> 16) | (u1 & 0xffff0000u);
        float r0 = v[2 * j]     - __uint_as_float(u0 & 0xffff0000u);
        float r1 = v[2 * j + 1] - __uint_as_float(u1 & 0xffff0000u);
        lw[j] = (__float_as_uint(r0) >> 16) | (__float_as_uint(r1) & 0xffff0000u);
    }
    uint4 h = make_uint4(hw[0], hw[1], hw[2], hw[3]);
    uint4 l = make_uint4(lw[0], lw[1], lw[2], lw[3]);
    hi = __builtin_bit_cast(bf16x8, h);
    lo = __builtin_bit_cast(bf16x8, l);
}

// ---------- K1: seg-side GEMM partials: segp[ks][n][col], 64 k-slices of 64 ----------
// grid (25, 64), block 256
__global__ void k_seg_gemm(const float* __restrict__ seg,
                           const float* __restrict__ iw1,
                           const float* __restrict__ rw1,
                           float* __restrict__ segp) {
    __shared__ float segT[64][5];    // [k][n], pad -> 2-way max on write
    int ng = blockIdx.x;
    int ks = blockIdx.y * 64;
    int tid = threadIdx.x;
    {
        int k = tid & 63, j = tid >> 6;
        segT[k][j] = seg[(size_t)(ng * 4 + j) * DDIM + ks + k];
    }
    __syncthreads();

    int col = tid;
    float a0 = 0.f, a1 = 0.f, a2 = 0.f, a3 = 0.f;
    const float* w = (col < HDIM) ? (iw1 + col)
                                  : (rw1 + (size_t)DDIM * HDIM + (col - HDIM));
    #pragma unroll 8
    for (int k = 0; k < 64; ++k) {
        float wv = w[(size_t)(ks + k) * HDIM];
        a0 = fmaf(segT[k][0], wv, a0);
        a1 = fmaf(segT[k][1], wv, a1);
        a2 = fmaf(segT[k][2], wv, a2);
        a3 = fmaf(segT[k][3], wv, a3);
    }
    float* outp = segp + (size_t)blockIdx.y * (NSEG * 256) + (size_t)(ng * 4) * 256 + col;
    outp[0] = a0; outp[256] = a1; outp[512] = a2; outp[768] = a3;
}

// ---------- K2: reduce 64 k-slices -> importance, coeff, shwT (transposed, +rb1) ----
// grid 100, block 256
__global__ void k_seg_red(const float* __restrict__ segp,
                          const int* __restrict__ positions,
                          const float* __restrict__ ib1,
                          const float* __restrict__ iw2,
                          const float* __restrict__ ib2,
                          const float* __restrict__ rb1,
                          float* __restrict__ shwT, float* __restrict__ impA,
                          float* __restrict__ cA) {
    __shared__ float red[HDIM];
    int n = blockIdx.x, tid = threadIdx.x;
    float v = 0.f;
    #pragma unroll
    for (int s = 0; s < 64; ++s)
        v += segp[(size_t)s * (NSEG * 256) + (size_t)n * 256 + tid];
    if (tid < HDIM) {
        red[tid] = gelu_f(v + ib1[tid]) * iw2[tid];
    } else {
        // transposed: shwT[h][n], h = tid-128
        shwT[(size_t)(tid - HDIM) * NSEG + n] = v + rb1[tid - HDIM];
    }
    __syncthreads();
    if (tid == 0) {
        float s = 0.f;
        for (int j = 0; j < HDIM; ++j) s += red[j];
        float imp = 1.f / (1.f + expf(-(s + ib2[0])));
        float pf = powf(0.95f, (float)NSEG - (float)positions[n] - 1.0f);
        impA[n] = imp;
        cA[n] = imp * (0.5f + 0.5f * pf);
    }
}

// ---------- K_bt: rw1[:D] -> transposed bf16 hi/lo pair Bt[128][4096] ----------
// grid 256 (k-chunks of 16), block 256
__global__ void k_bt(const float* __restrict__ rw1,
                     ushort* __restrict__ bth, ushort* __restrict__ btl) {
    __shared__ float tile[16][129];
    int tid = threadIdx.x;
    int k0 = blockIdx.x * 16;
    #pragma unroll
    for (int i = 0; i < 8; ++i) {
        int e = i * 256 + tid;
        int k = e >> 7, n = e & 127;
        tile[k][n] = rw1[(size_t)(k0 + k) * HDIM + n];
    }
    __syncthreads();
    int n = tid >> 1, kh = (tid & 1) * 8;
    uint hw[4], lw[4];
    #pragma unroll
    for (int j = 0; j < 4; ++j) {
        float x0 = tile[kh + 2 * j][n];
        float x1 = tile[kh + 2 * j + 1][n];
        uint u0 = __float_as_uint(x0), u1 = __float_as_uint(x1);
        hw[j] = (u0 >> 16) | (u1 & 0xffff0000u);
        float r0 = x0 - __uint_as_float(u0 & 0xffff0000u);
        float r1 = x1 - __uint_as_float(u1 & 0xffff0000u);
        lw[j] = (__float_as_uint(r0) >> 16) | (__float_as_uint(r1) & 0xffff0000u);
    }
    size_t o = (size_t)n * DDIM + k0 + kh;
    *reinterpret_cast<uint4*>(bth + o) = make_uint4(hw[0], hw[1], hw[2], hw[3]);
    *reinterpret_cast<uint4*>(btl + o) = make_uint4(lw[0], lw[1], lw[2], lw[3]);
}

// ---------- K3: qh via bf16x3 MFMA. grid (256, 16), block 64 (1 wave) ----------
// Wave: 16 rows x 128 cols x K=256 (8 steps of 32). 4096 waves = 4/SIMD (TLP
// hides load latency; per m114 wave-level overlap is automatic). acc = 32 VGPR.
__global__ __launch_bounds__(64)
void k_qh_mfma(const float* __restrict__ query,
               const ushort* __restrict__ bth,
               const ushort* __restrict__ btl,
               float* __restrict__ qhp) {
    int lane = threadIdx.x;
    int m0 = blockIdx.x * 16;
    int ky = blockIdx.y;
    int k0 = ky * 256;
    int cl = lane & 15;        // A row sel / B-col sel / C col
    int rg = lane >> 4;        // k-group 0..3

    f32x4 acc[8];
    #pragma unroll
    for (int nf = 0; nf < 8; ++nf) acc[nf] = (f32x4)0.f;

    const float*  ap  = query + (size_t)(m0 + cl) * DDIM + k0 + rg * 8;
    const ushort* bhp = bth + (size_t)cl * DDIM + k0 + rg * 8;
    const ushort* blp = btl + (size_t)cl * DDIM + k0 + rg * 8;

    #pragma unroll
    for (int ks = 0; ks < 8; ++ks) {
        float4 qa0 = *reinterpret_cast<const float4*>(ap + ks * 32);
        float4 qa1 = *reinterpret_cast<const float4*>(ap + ks * 32 + 4);
        bf16x8 ah, al;
        split8(qa0, qa1, ah, al);
        #pragma unroll
        for (int nf = 0; nf < 8; ++nf) {
            bf16x8 bh = *reinterpret_cast<const bf16x8*>(bhp + (size_t)nf * 16 * DDIM + ks * 32);
            bf16x8 bl = *reinterpret_cast<const bf16x8*>(blp + (size_t)nf * 16 * DDIM + ks * 32);
            acc[nf] = __builtin_amdgcn_mfma_f32_16x16x32_bf16(ah, bh, acc[nf], 0, 0, 0);
            acc[nf] = __builtin_amdgcn_mfma_f32_16x16x32_bf16(al, bh, acc[nf], 0, 0, 0);
            acc[nf] = __builtin_amdgcn_mfma_f32_16x16x32_bf16(ah, bl, acc[nf], 0, 0, 0);
        }
    }

    // C/D layout (measured m89): col = nf*16 + (lane&15), row = (lane>>4)*4 + reg
    float* op = qhp + (size_t)ky * (BROWS * HDIM);
    int rg4 = rg * 4;
    #pragma unroll
    for (int nf = 0; nf < 8; ++nf) {
        int col = nf * 16 + cl;
        #pragma unroll
        for (int r = 0; r < 4; ++r)
            op[(size_t)(m0 + rg4 + r) * HDIM + col] = acc[nf][r];
    }
}

// ---------- K4a: rel scores + fused top-10 -> idxA/wnA ----------
// grid 512, block 256: 8 query-rows per block; thread owns segment n, 4 rows.
// shwT read directly from global (coalesced over lane-consecutive n, L1/L2-hot).
// LDS = 12.3 KB -> high occupancy.
__global__ __launch_bounds__(256)
void k_rel(const float* __restrict__ qhp,
           const float* __restrict__ shwT,
           const float* __restrict__ rw2,
           const float* __restrict__ rb2,
           const float* __restrict__ impA,
           const float* __restrict__ cA,
           int* __restrict__ idxA,
           float* __restrict__ wnA) {
    __shared__ float qs[8][HDIM];
    __shared__ float scL[8][128], wiL[8][128];
    int tid = threadIdx.x;
    int b0 = blockIdx.x * 8;

    {   // stage qs: sum 16 split-k slices; one float4 per thread (8*128/4 = 256)
        int r = tid >> 5, h4 = (tid & 31) * 4;
        size_t o = (size_t)(b0 + r) * HDIM + h4;
        float4 v = *reinterpret_cast<const float4*>(qhp + o);
        #pragma unroll
        for (int s = 1; s < KSLICES; ++s) {
            float4 p = *reinterpret_cast<const float4*>(
                qhp + (size_t)s * (BROWS * HDIM) + o);
            v.x += p.x; v.y += p.y; v.z += p.z; v.w += p.w;
        }
        *reinterpret_cast<float4*>(&qs[r][h4]) = v;
    }
    __syncthreads();

    int n = tid & 127, g = tid >> 7;
    int nn = (n < NSEG) ? n : (NSEG - 1);   // clamp: lanes 100..127 duplicate, writes masked
    int r0 = g * 4;
    float a0 = 0.f, a1 = 0.f, a2 = 0.f, a3 = 0.f;
    #pragma unroll 2
    for (int h = 0; h < HDIM; ++h) {
        float s = shwT[h * NSEG + nn];      // coalesced per-lane, L1-hot
        float w = rw2[h];                   // wave-uniform -> scalar load
        a0 = fmaf(gelu_f(qs[r0 + 0][h] + s), w, a0);
        a1 = fmaf(gelu_f(qs[r0 + 1][h] + s), w, a1);
        a2 = fmaf(gelu_f(qs[r0 + 2][h] + s), w, a2);
        a3 = fmaf(gelu_f(qs[r0 + 3][h] + s), w, a3);
    }
    if (n < NSEG) {
        float rb2f = rb2[0];
        float ca = cA[n], ia = impA[n];
        float r_[4];
        r_[0] = 1.f / (1.f + expf(-(a0 + rb2f)));
        r_[1] = 1.f / (1.f + expf(-(a1 + rb2f)));
        r_[2] = 1.f / (1.f + expf(-(a2 + rb2f)));
        r_[3] = 1.f / (1.f + expf(-(a3 + rb2f)));
        #pragma unroll
        for (int r = 0; r < 4; ++r) {
            scL[r0 + r][n] = ca * r_[r];
            wiL[r0 + r][n] = ia * r_[r];
        }
    }
    __syncthreads();

    // fused top-k: wave w handles rows w and w+4 (register-only butterfly)
    int w = tid >> 6, lane = tid & 63;
    for (int rr = w; rr < 8; rr += 4) {
        float s1 = scL[rr][lane];
        float w1 = wiL[rr][lane];
        int i2 = lane + 64;
        float s2 = (i2 < NSEG) ? scL[rr][i2] : -1e30f;
        float w2 = (i2 < NSEG) ? wiL[rr][i2] : 0.f;

        float wv[TOPK]; int idxv[TOPK]; float wsum = 0.f;
        #pragma unroll
        for (int k = 0; k < TOPK; ++k) {
            float s; int i;
            if (s2 > s1) { s = s2; i = i2; } else { s = s1; i = lane; }
            #pragma unroll
            for (int off = 1; off < 64; off <<= 1) {
                float os = __shfl_xor(s, off);
                int oi = __shfl_xor(i, off);
                if (os > s || (os == s && oi < i)) { s = os; i = oi; }
            }
            float wi = __shfl((i < 64) ? w1 : w2, i & 63);
            idxv[k] = i; wv[k] = wi; wsum += wi;
            if (i == lane) s1 = -1e30f;
            if (i == i2)   s2 = -1e30f;
        }
        if (lane == 0) {
            int b = b0 + rr;
            float denom = wsum + 1e-8f;
            #pragma unroll
            for (int k = 0; k < TOPK; ++k) {
                idxA[b * TOPK + k] = idxv[k];
                wnA[b * TOPK + k]  = wv[k] / denom;
            }
        }
    }
}

// ---------- K4c: pure streaming gather: out = query + sum wn[k]*seg[idx[k]] ----------
// grid 4096, block 256. Weights/pointers via wave-uniform scalar loads; no LDS/barriers.
__global__ void k_gather(const float* __restrict__ query,
                         const float* __restrict__ seg,
                         const int* __restrict__ idxA,
                         const float* __restrict__ wnA,
                         float* __restrict__ out) {
    int b = blockIdx.x, tid = threadIdx.x;
    const int*   ip = idxA + b * TOPK;
    const float* wp = wnA  + b * TOPK;
    float wn[TOPK]; const float* srow[TOPK];
    #pragma unroll
    for (int k = 0; k < TOPK; ++k) {
        wn[k]   = wp[k];                          // uniform -> s_load
        srow[k] = seg + (size_t)ip[k] * DDIM;     // uniform -> s_load + sgpr addr
    }
    const float* qrow = query + (size_t)b * DDIM;
    float* orow = out + (size_t)b * DDIM;

    float4 q[4];
    #pragma unroll
    for (int c = 0; c < 4; ++c)
        q[c] = *reinterpret_cast<const float4*>(qrow + c * 1024 + tid * 4);
    #pragma unroll
    for (int k = 0; k < TOPK; ++k) {
        float4 s[4];
        #pragma unroll
        for (int c = 0; c < 4; ++c)
            s[c] = *reinterpret_cast<const float4*>(srow[k] + c * 1024 + tid * 4);
        #pragma unroll
        for (int c = 0; c < 4; ++c) {
            q[c].x = fmaf(wn[k], s[c].x, q[c].x);
            q[c].y = fmaf(wn[k], s[c].y, q[c].y);
            q[c].z = fmaf(wn[k], s[c].z, q[c].z);
            q[c].w = fmaf(wn[k], s[c].w, q[c].w);
        }
    }
    #pragma unroll
    for (int c = 0; c < 4; ++c)
        *reinterpret_cast<float4*>(orow + c * 1024 + tid * 4) = q[c];
}

extern "C" void kernel_launch(void* const* d_in, const int* in_sizes, int n_in,
                              void* d_out, int out_size, void* d_ws, size_t ws_size,
                              hipStream_t stream) {
    const float* query = (const float*)d_in[0];
    const float* seg   = (const float*)d_in[1];
    const int*   pos   = (const int*)d_in[2];
    const float* iw1   = (const float*)d_in[3];
    const float* ib1   = (const float*)d_in[4];
    const float* iw2   = (const float*)d_in[5];
    const float* ib2   = (const float*)d_in[6];
    const float* rw1   = (const float*)d_in[7];
    const float* rb1   = (const float*)d_in[8];
    const float* rw2   = (const float*)d_in[9];
    const float* rb2   = (const float*)d_in[10];
    float* out = (float*)d_out;

    char* ws = (char*)d_ws;
    // qhp (16 slices, 32 MiB) time-shares [0,32Mi) with segp (6.55 MB): segp is
    // dead after k_seg_red, qhp written only by k_qh_mfma (stream-ordered).
    float* qhp  = (float*)(ws);                                   // 16*4096*128*4 = 32 MiB
    float* segp = (float*)(ws);                                   // 6.55 MB (dead before qhp)
    ushort* bth = (ushort*)(ws + 32 * 1024 * 1024);               // 1 MiB
    ushort* btl = (ushort*)(ws + 33 * 1024 * 1024);               // 1 MiB
    float* shwT = (float*)(ws + 34 * 1024 * 1024);                // 128*100*4 = 51.2 KB
    float* impA = (float*)(ws + 34 * 1024 * 1024 + 64 * 1024);
    float* cA   = (float*)(ws + 34 * 1024 * 1024 + 64 * 1024 + 4096);
    int*   idxA = (int*)  (ws + 34 * 1024 * 1024 + 128 * 1024);   // 160 KB
    float* wnA  = (float*)(ws + 34 * 1024 * 1024 + 320 * 1024);   // 160 KB

    hipLaunchKernelGGL(k_seg_gemm, dim3(25, 64), dim3(256), 0, stream, seg, iw1, rw1, segp);
    hipLaunchKernelGGL(k_seg_red, dim3(NSEG), dim3(256), 0, stream,
                       segp, pos, ib1, iw2, ib2, rb1, shwT, impA, cA);
    hipLaunchKernelGGL(k_bt, dim3(256), dim3(256), 0, stream, rw1, bth, btl);
    hipLaunchKernelGGL(k_qh_mfma, dim3(256, KSLICES), dim3(64), 0, stream,
                       query, bth, btl, qhp);
    hipLaunchKernelGGL(k_rel, dim3(BROWS / 8), dim3(256), 0, stream,
                       qhp, shwT, rw2, rb2, impA, cA, idxA, wnA);
    hipLaunchKernelGGL(k_gather, dim3(BROWS), dim3(256), 0, stream,
                       query, seg, idxA, wnA, out);
}

// Round 7
// 140.443 us; speedup vs baseline: 1.3400x; 1.3400x over previous
//
#include <hip/hip_runtime.h>
#include <math.h>

#define DDIM 4096
#define NSEG 100
#define HDIM 128
#define BROWS 4096
#define TOPK 10
#define KSLICES 8

typedef __attribute__((ext_vector_type(8))) short bf16x8;
typedef __attribute__((ext_vector_type(4))) float f32x4;

// async global->LDS, 16 B per lane; dest = uniform base + lane*16 (HW rule).
__device__ __forceinline__ void gl16(const void* g, void* l) {
    __builtin_amdgcn_global_load_lds(
        (const __attribute__((address_space(1))) unsigned int*)g,
        (__attribute__((address_space(3))) unsigned int*)l,
        16, 0, 0);
}

// Branch-free gelu: A&S 7.1.26 erf (abs err <= 1.5e-7), v_exp_f32 + v_rcp_f32.
__device__ __forceinline__ float gelu_f(float x) {
    float u  = x * 0.70710678118654752440f;
    float au = fminf(fabsf(u), 3.9f);                 // erf(3.9) == 1 to fp32
    float t  = __builtin_amdgcn_rcpf(fmaf(0.3275911f, au, 1.0f));
    float p  = fmaf(fmaf(fmaf(fmaf(1.061405429f, t, -1.453152027f), t,
                              1.421413741f), t, -0.284496736f), t, 0.254829592f) * t;
    float e  = __expf(-au * au);
    float er = fmaf(-p, e, 1.0f);                     // erf(|u|)
    er = copysignf(er, u);
    return 0.5f * x * (1.0f + er);
}

// Split fp32 -> bf16 hi (truncate) + bf16 lo (exact residual, truncated).
__device__ __forceinline__ void split8(const float4& a, const float4& b,
                                       bf16x8& hi, bf16x8& lo) {
    float v[8] = {a.x, a.y, a.z, a.w, b.x, b.y, b.z, b.w};
    uint hw[4], lw[4];
    #pragma unroll
    for (int j = 0; j < 4; ++j) {
        uint u0 = __float_as_uint(v[2 * j]);
        uint u1 = __float_as_uint(v[2 * j + 1]);
        hw[j] = (u0 >> 16) | (u1 & 0xffff0000u);
        float r0 = v[2 * j]     - __uint_as_float(u0 & 0xffff0000u);
        float r1 = v[2 * j + 1] - __uint_as_float(u1 & 0xffff0000u);
        lw[j] = (__float_as_uint(r0) >> 16) | (__float_as_uint(r1) & 0xffff0000u);
    }
    uint4 h = make_uint4(hw[0], hw[1], hw[2], hw[3]);
    uint4 l = make_uint4(lw[0], lw[1], lw[2], lw[3]);
    hi = __builtin_bit_cast(bf16x8, h);
    lo = __builtin_bit_cast(bf16x8, l);
}

// ---------- K1: seg-side GEMM partials: segp[ks][n][col], 64 k-slices of 64 ----------
// grid (25, 64), block 256
__global__ void k_seg_gemm(const float* __restrict__ seg,
                           const float* __restrict__ iw1,
                           const float* __restrict__ rw1,
                           float* __restrict__ segp) {
    __shared__ float segT[64][5];    // [k][n], pad -> 2-way max on write
    int ng = blockIdx.x;
    int ks = blockIdx.y * 64;
    int tid = threadIdx.x;
    {
        int k = tid & 63, j = tid >> 6;
        segT[k][j] = seg[(size_t)(ng * 4 + j) * DDIM + ks + k];
    }
    __syncthreads();

    int col = tid;
    float a0 = 0.f, a1 = 0.f, a2 = 0.f, a3 = 0.f;
    const float* w = (col < HDIM) ? (iw1 + col)
                                  : (rw1 + (size_t)DDIM * HDIM + (col - HDIM));
    #pragma unroll 8
    for (int k = 0; k < 64; ++k) {
        float wv = w[(size_t)(ks + k) * HDIM];
        a0 = fmaf(segT[k][0], wv, a0);
        a1 = fmaf(segT[k][1], wv, a1);
        a2 = fmaf(segT[k][2], wv, a2);
        a3 = fmaf(segT[k][3], wv, a3);
    }
    float* outp = segp + (size_t)blockIdx.y * (NSEG * 256) + (size_t)(ng * 4) * 256 + col;
    outp[0] = a0; outp[256] = a1; outp[512] = a2; outp[768] = a3;
}

// ---------- K2: reduce 64 k-slices -> importance, coeff, shwT (transposed, +rb1) ----
// grid 100, block 256
__global__ void k_seg_red(const float* __restrict__ segp,
                          const int* __restrict__ positions,
                          const float* __restrict__ ib1,
                          const float* __restrict__ iw2,
                          const float* __restrict__ ib2,
                          const float* __restrict__ rb1,
                          float* __restrict__ shwT, float* __restrict__ impA,
                          float* __restrict__ cA) {
    __shared__ float red[HDIM];
    int n = blockIdx.x, tid = threadIdx.x;
    float v = 0.f;
    #pragma unroll
    for (int s = 0; s < 64; ++s)
        v += segp[(size_t)s * (NSEG * 256) + (size_t)n * 256 + tid];
    if (tid < HDIM) {
        red[tid] = gelu_f(v + ib1[tid]) * iw2[tid];
    } else {
        // transposed: shwT[h][n], h = tid-128
        shwT[(size_t)(tid - HDIM) * NSEG + n] = v + rb1[tid - HDIM];
    }
    __syncthreads();
    if (tid == 0) {
        float s = 0.f;
        for (int j = 0; j < HDIM; ++j) s += red[j];
        float imp = 1.f / (1.f + expf(-(s + ib2[0])));
        float pf = powf(0.95f, (float)NSEG - (float)positions[n] - 1.0f);
        impA[n] = imp;
        cA[n] = imp * (0.5f + 0.5f * pf);
    }
}

// ---------- K_bt: rw1[:D] -> per-K-chunk pre-swizzled LDS images ----------
// btI[chunk c][0..8191]   = hi bf16 image, byte Z(col,u) = (col*64+u*16)^((col&7)<<4)
// btI[chunk c][8192..16383] = lo image (same Z).
// At Z: 8 bf16 of column col, k = c*32 + u*8 .. +8.  grid 128, block 256.
__global__ void k_bt(const float* __restrict__ rw1,
                     unsigned char* __restrict__ btI) {
    __shared__ float tile[32][129];
    int c = blockIdx.x, tid = threadIdx.x;
    #pragma unroll
    for (int i = 0; i < 4; ++i) {
        int e = i * 1024 + tid * 4;
        int k = e >> 7, n = e & 127;
        *reinterpret_cast<float4*>(&tile[k][n]) =
            *reinterpret_cast<const float4*>(rw1 + (size_t)(c * 32 + k) * HDIM + n);
    }
    __syncthreads();
    unsigned char* img = btI + (size_t)c * 16384;
    #pragma unroll
    for (int uu = 0; uu < 2; ++uu) {
        int U = tid * 2 + uu;            // 0..511
        int col = U >> 2;
        int u = U & 3;
        int Z = (col * 64 + u * 16) ^ ((col & 7) << 4);
        uint hw[4], lw[4];
        #pragma unroll
        for (int j = 0; j < 4; ++j) {
            float x0 = tile[u * 8 + 2 * j][col];
            float x1 = tile[u * 8 + 2 * j + 1][col];
            uint u0 = __float_as_uint(x0), u1 = __float_as_uint(x1);
            hw[j] = (u0 >> 16) | (u1 & 0xffff0000u);
            float r0 = x0 - __uint_as_float(u0 & 0xffff0000u);
            float r1 = x1 - __uint_as_float(u1 & 0xffff0000u);
            lw[j] = (__float_as_uint(r0) >> 16) | (__float_as_uint(r1) & 0xffff0000u);
        }
        *reinterpret_cast<uint4*>(img + Z)        = make_uint4(hw[0], hw[1], hw[2], hw[3]);
        *reinterpret_cast<uint4*>(img + 8192 + Z) = make_uint4(lw[0], lw[1], lw[2], lw[3]);
    }
}

// ---------- K3: qh via bf16x3 MFMA, m97-style global_load_lds double-buffer ----------
// grid (64, 8), block 256 (4 waves). Block: 64 rows x 128 cols x K=512 (16 steps of 32).
// A staged linear-dest + inverse-swizzled source (byte^=(row&7)<<4); B staged linearly
// from the pre-swizzled btI image. 2-phase loop: stage(t+1) -> compute(t) -> barrier.
__global__ __launch_bounds__(256)
void k_qh_mfma(const float* __restrict__ query,
               const unsigned char* __restrict__ btI,
               float* __restrict__ qhp) {
    __shared__ float  Ab[2][2048];     // [buf][64 rows x 32 k] swizzled, 8 KB each
    __shared__ ushort Bb[2][8192];     // [buf][hi 8KB | lo 8KB], 16 KB each
    int tid = threadIdx.x;
    int lane = tid & 63, w = tid >> 6;
    int cl = lane & 15, rg = lane >> 4;
    int wm = w >> 1, wn = w & 1;       // wave quadrant: 32 rows x 64 cols
    int m0 = blockIdx.x * 64;
    int ky = blockIdx.y;
    int k0 = ky * 512;

    // A staging: 2 instr/wave. LDS byte X = w*2048 + i*1024 + lane*16 (linear).
    // Source inverse-swizzle: row = X>>7, kb = (X&127) ^ ((row&7)<<4).
    const float* aSrc0;
    const float* aSrc1;
    {
        int X0 = w * 2048 + lane * 16;
        int r0_ = X0 >> 7, kb0 = (X0 & 127) ^ ((r0_ & 7) << 4);
        aSrc0 = query + (size_t)(m0 + r0_) * DDIM + k0 + (kb0 >> 2);
        int X1 = X0 + 1024;
        int r1_ = X1 >> 7, kb1 = (X1 & 127) ^ ((r1_ & 7) << 4);
        aSrc1 = query + (size_t)(m0 + r1_) * DDIM + k0 + (kb1 >> 2);
    }
    // B staging: 4 instr/wave, pure linear copy of the image chunk.
    const unsigned char* bSrc = btI + (size_t)(ky * 16) * 16384 + w * 4096 + lane * 16;

    f32x4 acc[2][4];
    #pragma unroll
    for (int mi = 0; mi < 2; ++mi)
        #pragma unroll
        for (int nf = 0; nf < 4; ++nf) acc[mi][nf] = (f32x4)0.f;

    // prologue: stage t=0 into buf 0
    {
        char* ad = (char*)&Ab[0][0] + w * 2048;
        char* bd = (char*)&Bb[0][0] + w * 4096;
        gl16(aSrc0, ad);
        gl16(aSrc1, ad + 1024);
        #pragma unroll
        for (int j = 0; j < 4; ++j) gl16(bSrc + j * 1024, bd + j * 1024);
    }
    __syncthreads();

    #pragma unroll 2
    for (int t = 0; t < 16; ++t) {
        int cur = t & 1;
        if (t < 15) {   // stage t+1 into other buffer (async, drains at barrier)
            char* ad = (char*)&Ab[cur ^ 1][0] + w * 2048;
            char* bd = (char*)&Bb[cur ^ 1][0] + w * 4096;
            gl16(aSrc0 + (t + 1) * 32, ad);
            gl16(aSrc1 + (t + 1) * 32, ad + 1024);
            const unsigned char* bs = bSrc + (size_t)(t + 1) * 16384;
            #pragma unroll
            for (int j = 0; j < 4; ++j) gl16(bs + j * 1024, bd + j * 1024);
        }
        // compute from buf cur
        bf16x8 ah[2], al[2];
        #pragma unroll
        for (int mi = 0; mi < 2; ++mi) {
            int row = wm * 32 + mi * 16 + cl;
            int sw = (row & 7) << 4;
            int Sb = row * 128 + rg * 32;
            float4 f0 = *reinterpret_cast<const float4*>((const char*)&Ab[cur][0] + (Sb ^ sw));
            float4 f1 = *reinterpret_cast<const float4*>((const char*)&Ab[cur][0] + ((Sb + 16) ^ sw));
            split8(f0, f1, ah[mi], al[mi]);
        }
        #pragma unroll
        for (int nf = 0; nf < 4; ++nf) {
            int col = wn * 64 + nf * 16 + cl;
            int Z = (col * 64 + rg * 16) ^ ((col & 7) << 4);
            bf16x8 bh = *reinterpret_cast<const bf16x8*>((const char*)&Bb[cur][0] + Z);
            bf16x8 bl = *reinterpret_cast<const bf16x8*>((const char*)&Bb[cur][0] + 8192 + Z);
            #pragma unroll
            for (int mi = 0; mi < 2; ++mi) {
                acc[mi][nf] = __builtin_amdgcn_mfma_f32_16x16x32_bf16(ah[mi], bh, acc[mi][nf], 0, 0, 0);
                acc[mi][nf] = __builtin_amdgcn_mfma_f32_16x16x32_bf16(al[mi], bh, acc[mi][nf], 0, 0, 0);
                acc[mi][nf] = __builtin_amdgcn_mfma_f32_16x16x32_bf16(ah[mi], bl, acc[mi][nf], 0, 0, 0);
            }
        }
        __syncthreads();
    }

    // C/D layout (measured m89): col = lane&15 within frag, row = (lane>>4)*4 + reg
    float* op = qhp + (size_t)ky * (BROWS * HDIM);
    #pragma unroll
    for (int mi = 0; mi < 2; ++mi) {
        int rowb = m0 + wm * 32 + mi * 16 + rg * 4;
        #pragma unroll
        for (int nf = 0; nf < 4; ++nf) {
            int col = wn * 64 + nf * 16 + cl;
            #pragma unroll
            for (int r = 0; r < 4; ++r)
                op[(size_t)(rowb + r) * HDIM + col] = acc[mi][nf][r];
        }
    }
}

// ---------- K4a: rel scores + fused top-10 -> idxA/wnA ----------
// grid 512, block 256: 8 query-rows per block; thread owns segment n, 4 rows.
__global__ __launch_bounds__(256)
void k_rel(const float* __restrict__ qhp,
           const float* __restrict__ shwT,
           const float* __restrict__ rw2,
           const float* __restrict__ rb2,
           const float* __restrict__ impA,
           const float* __restrict__ cA,
           int* __restrict__ idxA,
           float* __restrict__ wnA) {
    __shared__ float qs[8][HDIM];
    __shared__ float scL[8][128], wiL[8][128];
    int tid = threadIdx.x;
    int b0 = blockIdx.x * 8;

    {   // stage qs: sum split-k slices; one float4 per thread (8*128/4 = 256)
        int r = tid >> 5, h4 = (tid & 31) * 4;
        size_t o = (size_t)(b0 + r) * HDIM + h4;
        float4 v = *reinterpret_cast<const float4*>(qhp + o);
        #pragma unroll
        for (int s = 1; s < KSLICES; ++s) {
            float4 p = *reinterpret_cast<const float4*>(
                qhp + (size_t)s * (BROWS * HDIM) + o);
            v.x += p.x; v.y += p.y; v.z += p.z; v.w += p.w;
        }
        *reinterpret_cast<float4*>(&qs[r][h4]) = v;
    }
    __syncthreads();

    int n = tid & 127, g = tid >> 7;
    int nn = (n < NSEG) ? n : (NSEG - 1);   // clamp: lanes 100..127 duplicate, writes masked
    int r0 = g * 4;
    float a0 = 0.f, a1 = 0.f, a2 = 0.f, a3 = 0.f;
    #pragma unroll 2
    for (int h = 0; h < HDIM; ++h) {
        float s = shwT[h * NSEG + nn];      // coalesced per-lane, L1-hot
        float w = rw2[h];                   // wave-uniform -> scalar load
        a0 = fmaf(gelu_f(qs[r0 + 0][h] + s), w, a0);
        a1 = fmaf(gelu_f(qs[r0 + 1][h] + s), w, a1);
        a2 = fmaf(gelu_f(qs[r0 + 2][h] + s), w, a2);
        a3 = fmaf(gelu_f(qs[r0 + 3][h] + s), w, a3);
    }
    if (n < NSEG) {
        float rb2f = rb2[0];
        float ca = cA[n], ia = impA[n];
        float r_[4];
        r_[0] = 1.f / (1.f + expf(-(a0 + rb2f)));
        r_[1] = 1.f / (1.f + expf(-(a1 + rb2f)));
        r_[2] = 1.f / (1.f + expf(-(a2 + rb2f)));
        r_[3] = 1.f / (1.f + expf(-(a3 + rb2f)));
        #pragma unroll
        for (int r = 0; r < 4; ++r) {
            scL[r0 + r][n] = ca * r_[r];
            wiL[r0 + r][n] = ia * r_[r];
        }
    }
    __syncthreads();

    // fused top-k: wave w handles rows w and w+4 (register-only butterfly)
    int w = tid >> 6, lane = tid & 63;
    for (int rr = w; rr < 8; rr += 4) {
        float s1 = scL[rr][lane];
        float w1 = wiL[rr][lane];
        int i2 = lane + 64;
        float s2 = (i2 < NSEG) ? scL[rr][i2] : -1e30f;
        float w2 = (i2 < NSEG) ? wiL[rr][i2] : 0.f;

        float wv[TOPK]; int idxv[TOPK]; float wsum = 0.f;
        #pragma unroll
        for (int k = 0; k < TOPK; ++k) {
            float s; int i;
            if (s2 > s1) { s = s2; i = i2; } else { s = s1; i = lane; }
            #pragma unroll
            for (int off = 1; off < 64; off <<= 1) {
                float os = __shfl_xor(s, off);
                int oi = __shfl_xor(i, off);
                if (os > s || (os == s && oi < i)) { s = os; i = oi; }
            }
            float wi = __shfl((i < 64) ? w1 : w2, i & 63);
            idxv[k] = i; wv[k] = wi; wsum += wi;
            if (i == lane) s1 = -1e30f;
            if (i == i2)   s2 = -1e30f;
        }
        if (lane == 0) {
            int b = b0 + rr;
            float denom = wsum + 1e-8f;
            #pragma unroll
            for (int k = 0; k < TOPK; ++k) {
                idxA[b * TOPK + k] = idxv[k];
                wnA[b * TOPK + k]  = wv[k] / denom;
            }
        }
    }
}

// ---------- K4c: pure streaming gather: out = query + sum wn[k]*seg[idx[k]] ----------
// grid 4096, block 256. Weights/pointers via wave-uniform scalar loads; no LDS/barriers.
__global__ void k_gather(const float* __restrict__ query,
                         const float* __restrict__ seg,
                         const int* __restrict__ idxA,
                         const float* __restrict__ wnA,
                         float* __restrict__ out) {
    int b = blockIdx.x, tid = threadIdx.x;
    const int*   ip = idxA + b * TOPK;
    const float* wp = wnA  + b * TOPK;
    float wn[TOPK]; const float* srow[TOPK];
    #pragma unroll
    for (int k = 0; k < TOPK; ++k) {
        wn[k]   = wp[k];                          // uniform -> s_load
        srow[k] = seg + (size_t)ip[k] * DDIM;     // uniform -> s_load + sgpr addr
    }
    const float* qrow = query + (size_t)b * DDIM;
    float* orow = out + (size_t)b * DDIM;

    float4 q[4];
    #pragma unroll
    for (int c = 0; c < 4; ++c)
        q[c] = *reinterpret_cast<const float4*>(qrow + c * 1024 + tid * 4);
    #pragma unroll
    for (int k = 0; k < TOPK; ++k) {
        float4 s[4];
        #pragma unroll
        for (int c = 0; c < 4; ++c)
            s[c] = *reinterpret_cast<const float4*>(srow[k] + c * 1024 + tid * 4);
        #pragma unroll
        for (int c = 0; c < 4; ++c) {
            q[c].x = fmaf(wn[k], s[c].x, q[c].x);
            q[c].y = fmaf(wn[k], s[c].y, q[c].y);
            q[c].z = fmaf(wn[k], s[c].z, q[c].z);
            q[c].w = fmaf(wn[k], s[c].w, q[c].w);
        }
    }
    #pragma unroll
    for (int c = 0; c < 4; ++c)
        *reinterpret_cast<float4*>(orow + c * 1024 + tid * 4) = q[c];
}

extern "C" void kernel_launch(void* const* d_in, const int* in_sizes, int n_in,
                              void* d_out, int out_size, void* d_ws, size_t ws_size,
                              hipStream_t stream) {
    const float* query = (const float*)d_in[0];
    const float* seg   = (const float*)d_in[1];
    const int*   pos   = (const int*)d_in[2];
    const float* iw1   = (const float*)d_in[3];
    const float* ib1   = (const float*)d_in[4];
    const float* iw2   = (const float*)d_in[5];
    const float* ib2   = (const float*)d_in[6];
    const float* rw1   = (const float*)d_in[7];
    const float* rb1   = (const float*)d_in[8];
    const float* rw2   = (const float*)d_in[9];
    const float* rb2   = (const float*)d_in[10];
    float* out = (float*)d_out;

    char* ws = (char*)d_ws;
    // qhp (8 slices, 16 MiB) time-shares [0,16Mi) with segp (6.55 MB): segp dead
    // after k_seg_red; qhp written only by k_qh_mfma (stream-ordered).
    float* qhp  = (float*)(ws);                                   // 8*4096*128*4 = 16 MiB
    float* segp = (float*)(ws);                                   // 6.55 MB (dead before qhp)
    unsigned char* btI = (unsigned char*)(ws + 16 * 1024 * 1024); // 128 chunks * 16 KB = 2 MiB
    float* shwT = (float*)(ws + 18 * 1024 * 1024);                // 128*100*4 = 51.2 KB
    float* impA = (float*)(ws + 18 * 1024 * 1024 + 64 * 1024);
    float* cA   = (float*)(ws + 18 * 1024 * 1024 + 64 * 1024 + 4096);
    int*   idxA = (int*)  (ws + 18 * 1024 * 1024 + 128 * 1024);   // 160 KB
    float* wnA  = (float*)(ws + 18 * 1024 * 1024 + 320 * 1024);   // 160 KB

    hipLaunchKernelGGL(k_seg_gemm, dim3(25, 64), dim3(256), 0, stream, seg, iw1, rw1, segp);
    hipLaunchKernelGGL(k_seg_red, dim3(NSEG), dim3(256), 0, stream,
                       segp, pos, ib1, iw2, ib2, rb1, shwT, impA, cA);
    hipLaunchKernelGGL(k_bt, dim3(128), dim3(256), 0, stream, rw1, btI);
    hipLaunchKernelGGL(k_qh_mfma, dim3(64, KSLICES), dim3(256), 0, stream,
                       query, btI, qhp);
    hipLaunchKernelGGL(k_rel, dim3(BROWS / 8), dim3(256), 0, stream,
                       qhp, shwT, rw2, rb2, impA, cA, idxA, wnA);
    hipLaunchKernelGGL(k_gather, dim3(BROWS), dim3(256), 0, stream,
                       query, seg, idxA, wnA, out);
}

// Round 8
// 135.840 us; speedup vs baseline: 1.3854x; 1.0339x over previous
//
#include <hip/hip_runtime.h>
#include <math.h>

#define DDIM 4096
#define NSEG 100
#define HDIM 128
#define BROWS 4096
#define TOPK 10
#define KSLICES 8

typedef __attribute__((ext_vector_type(8))) short bf16x8;
typedef __attribute__((ext_vector_type(4))) float f32x4;

// async global->LDS, 16 B per lane; dest = uniform base + lane*16 (HW rule).
__device__ __forceinline__ void gl16(const void* g, void* l) {
    __builtin_amdgcn_global_load_lds(
        (const __attribute__((address_space(1))) unsigned int*)g,
        (__attribute__((address_space(3))) unsigned int*)l,
        16, 0, 0);
}

// Branch-free gelu: A&S 7.1.26 erf (abs err <= 1.5e-7), v_exp_f32 + v_rcp_f32.
__device__ __forceinline__ float gelu_f(float x) {
    float u  = x * 0.70710678118654752440f;
    float au = fminf(fabsf(u), 3.9f);                 // erf(3.9) == 1 to fp32
    float t  = __builtin_amdgcn_rcpf(fmaf(0.3275911f, au, 1.0f));
    float p  = fmaf(fmaf(fmaf(fmaf(1.061405429f, t, -1.453152027f), t,
                              1.421413741f), t, -0.284496736f), t, 0.254829592f) * t;
    float e  = __expf(-au * au);
    float er = fmaf(-p, e, 1.0f);                     // erf(|u|)
    er = copysignf(er, u);
    return 0.5f * x * (1.0f + er);
}

// Split fp32 -> bf16 hi (truncate) + bf16 lo (exact residual, truncated).
__device__ __forceinline__ void split8(const float4& a, const float4& b,
                                       bf16x8& hi, bf16x8& lo) {
    float v[8] = {a.x, a.y, a.z, a.w, b.x, b.y, b.z, b.w};
    uint hw[4], lw[4];
    #pragma unroll
    for (int j = 0; j < 4; ++j) {
        uint u0 = __float_as_uint(v[2 * j]);
        uint u1 = __float_as_uint(v[2 * j + 1]);
        hw[j] = (u0 >> 16) | (u1 & 0xffff0000u);
        float r0 = v[2 * j]     - __uint_as_float(u0 & 0xffff0000u);
        float r1 = v[2 * j + 1] - __uint_as_float(u1 & 0xffff0000u);
        lw[j] = (__float_as_uint(r0) >> 16) | (__float_as_uint(r1) & 0xffff0000u);
    }
    uint4 h = make_uint4(hw[0], hw[1], hw[2], hw[3]);
    uint4 l = make_uint4(lw[0], lw[1], lw[2], lw[3]);
    hi = __builtin_bit_cast(bf16x8, h);
    lo = __builtin_bit_cast(bf16x8, l);
}

// ---------- K1: seg-side GEMM partials: segp[ks][n][col], 64 k-slices of 64 ----------
// grid (25, 64), block 256
__global__ void k_seg_gemm(const float* __restrict__ seg,
                           const float* __restrict__ iw1,
                           const float* __restrict__ rw1,
                           float* __restrict__ segp) {
    __shared__ float segT[64][5];    // [k][n], pad -> 2-way max on write
    int ng = blockIdx.x;
    int ks = blockIdx.y * 64;
    int tid = threadIdx.x;
    {
        int k = tid & 63, j = tid >> 6;
        segT[k][j] = seg[(size_t)(ng * 4 + j) * DDIM + ks + k];
    }
    __syncthreads();

    int col = tid;
    float a0 = 0.f, a1 = 0.f, a2 = 0.f, a3 = 0.f;
    const float* w = (col < HDIM) ? (iw1 + col)
                                  : (rw1 + (size_t)DDIM * HDIM + (col - HDIM));
    #pragma unroll 8
    for (int k = 0; k < 64; ++k) {
        float wv = w[(size_t)(ks + k) * HDIM];
        a0 = fmaf(segT[k][0], wv, a0);
        a1 = fmaf(segT[k][1], wv, a1);
        a2 = fmaf(segT[k][2], wv, a2);
        a3 = fmaf(segT[k][3], wv, a3);
    }
    float* outp = segp + (size_t)blockIdx.y * (NSEG * 256) + (size_t)(ng * 4) * 256 + col;
    outp[0] = a0; outp[256] = a1; outp[512] = a2; outp[768] = a3;
}

// ---------- K2: reduce 64 k-slices -> importance, coeff, shwT (transposed, +rb1) ----
// grid 100, block 256
__global__ void k_seg_red(const float* __restrict__ segp,
                          const int* __restrict__ positions,
                          const float* __restrict__ ib1,
                          const float* __restrict__ iw2,
                          const float* __restrict__ ib2,
                          const float* __restrict__ rb1,
                          float* __restrict__ shwT, float* __restrict__ impA,
                          float* __restrict__ cA) {
    __shared__ float red[HDIM];
    int n = blockIdx.x, tid = threadIdx.x;
    float v = 0.f;
    #pragma unroll
    for (int s = 0; s < 64; ++s)
        v += segp[(size_t)s * (NSEG * 256) + (size_t)n * 256 + tid];
    if (tid < HDIM) {
        red[tid] = gelu_f(v + ib1[tid]) * iw2[tid];
    } else {
        // transposed: shwT[h][n], h = tid-128
        shwT[(size_t)(tid - HDIM) * NSEG + n] = v + rb1[tid - HDIM];
    }
    __syncthreads();
    if (tid == 0) {
        float s = 0.f;
        for (int j = 0; j < HDIM; ++j) s += red[j];
        float imp = 1.f / (1.f + expf(-(s + ib2[0])));
        float pf = powf(0.95f, (float)NSEG - (float)positions[n] - 1.0f);
        impA[n] = imp;
        cA[n] = imp * (0.5f + 0.5f * pf);
    }
}

// ---------- K_bt: rw1[:D] -> per-K-chunk pre-swizzled LDS images ----------
// btI[chunk c][0..8191]   = hi bf16 image, byte Z(col,u) = (col*64+u*16)^((col&7)<<4)
// btI[chunk c][8192..16383] = lo image (same Z).
// At Z: 8 bf16 of column col, k = c*32 + u*8 .. +8.  grid 128, block 256.
__global__ void k_bt(const float* __restrict__ rw1,
                     unsigned char* __restrict__ btI) {
    __shared__ float tile[32][129];
    int c = blockIdx.x, tid = threadIdx.x;
    #pragma unroll
    for (int i = 0; i < 4; ++i) {
        int e = i * 1024 + tid * 4;
        int k = e >> 7, n = e & 127;
        *reinterpret_cast<float4*>(&tile[k][n]) =
            *reinterpret_cast<const float4*>(rw1 + (size_t)(c * 32 + k) * HDIM + n);
    }
    __syncthreads();
    unsigned char* img = btI + (size_t)c * 16384;
    #pragma unroll
    for (int uu = 0; uu < 2; ++uu) {
        int U = tid * 2 + uu;            // 0..511
        int col = U >> 2;
        int u = U & 3;
        int Z = (col * 64 + u * 16) ^ ((col & 7) << 4);
        uint hw[4], lw[4];
        #pragma unroll
        for (int j = 0; j < 4; ++j) {
            float x0 = tile[u * 8 + 2 * j][col];
            float x1 = tile[u * 8 + 2 * j + 1][col];
            uint u0 = __float_as_uint(x0), u1 = __float_as_uint(x1);
            hw[j] = (u0 >> 16) | (u1 & 0xffff0000u);
            float r0 = x0 - __uint_as_float(u0 & 0xffff0000u);
            float r1 = x1 - __uint_as_float(u1 & 0xffff0000u);
            lw[j] = (__float_as_uint(r0) >> 16) | (__float_as_uint(r1) & 0xffff0000u);
        }
        *reinterpret_cast<uint4*>(img + Z)        = make_uint4(hw[0], hw[1], hw[2], hw[3]);
        *reinterpret_cast<uint4*>(img + 8192 + Z) = make_uint4(lw[0], lw[1], lw[2], lw[3]);
    }
}

// ---------- K3: qh via bf16x3 MFMA, m97-style global_load_lds double-buffer ----------
// grid (64, 8), block 256 (4 waves). Block: 64 rows x 128 cols x K=512 (16 steps of 32).
// A staged linear-dest + inverse-swizzled source (byte^=(row&7)<<4); B staged linearly
// from the pre-swizzled btI image. 2-phase loop: stage(t+1) -> compute(t) -> barrier.
__global__ __launch_bounds__(256)
void k_qh_mfma(const float* __restrict__ query,
               const unsigned char* __restrict__ btI,
               float* __restrict__ qhp) {
    __shared__ float  Ab[2][2048];     // [buf][64 rows x 32 k] swizzled, 8 KB each
    __shared__ ushort Bb[2][8192];     // [buf][hi 8KB | lo 8KB], 16 KB each
    int tid = threadIdx.x;
    int lane = tid & 63, w = tid >> 6;
    int cl = lane & 15, rg = lane >> 4;
    int wm = w >> 1, wn = w & 1;       // wave quadrant: 32 rows x 64 cols
    int m0 = blockIdx.x * 64;
    int ky = blockIdx.y;
    int k0 = ky * 512;

    // A staging: 2 instr/wave. LDS byte X = w*2048 + i*1024 + lane*16 (linear).
    // Source inverse-swizzle: row = X>>7, kb = (X&127) ^ ((row&7)<<4).
    const float* aSrc0;
    const float* aSrc1;
    {
        int X0 = w * 2048 + lane * 16;
        int r0_ = X0 >> 7, kb0 = (X0 & 127) ^ ((r0_ & 7) << 4);
        aSrc0 = query + (size_t)(m0 + r0_) * DDIM + k0 + (kb0 >> 2);
        int X1 = X0 + 1024;
        int r1_ = X1 >> 7, kb1 = (X1 & 127) ^ ((r1_ & 7) << 4);
        aSrc1 = query + (size_t)(m0 + r1_) * DDIM + k0 + (kb1 >> 2);
    }
    // B staging: 4 instr/wave, pure linear copy of the image chunk.
    const unsigned char* bSrc = btI + (size_t)(ky * 16) * 16384 + w * 4096 + lane * 16;

    f32x4 acc[2][4];
    #pragma unroll
    for (int mi = 0; mi < 2; ++mi)
        #pragma unroll
        for (int nf = 0; nf < 4; ++nf) acc[mi][nf] = (f32x4)0.f;

    // prologue: stage t=0 into buf 0
    {
        char* ad = (char*)&Ab[0][0] + w * 2048;
        char* bd = (char*)&Bb[0][0] + w * 4096;
        gl16(aSrc0, ad);
        gl16(aSrc1, ad + 1024);
        #pragma unroll
        for (int j = 0; j < 4; ++j) gl16(bSrc + j * 1024, bd + j * 1024);
    }
    __syncthreads();

    #pragma unroll 2
    for (int t = 0; t < 16; ++t) {
        int cur = t & 1;
        if (t < 15) {   // stage t+1 into other buffer (async, drains at barrier)
            char* ad = (char*)&Ab[cur ^ 1][0] + w * 2048;
            char* bd = (char*)&Bb[cur ^ 1][0] + w * 4096;
            gl16(aSrc0 + (t + 1) * 32, ad);
            gl16(aSrc1 + (t + 1) * 32, ad + 1024);
            const unsigned char* bs = bSrc + (size_t)(t + 1) * 16384;
            #pragma unroll
            for (int j = 0; j < 4; ++j) gl16(bs + j * 1024, bd + j * 1024);
        }
        // compute from buf cur
        bf16x8 ah[2], al[2];
        #pragma unroll
        for (int mi = 0; mi < 2; ++mi) {
            int row = wm * 32 + mi * 16 + cl;
            int sw = (row & 7) << 4;
            int Sb = row * 128 + rg * 32;
            float4 f0 = *reinterpret_cast<const float4*>((const char*)&Ab[cur][0] + (Sb ^ sw));
            float4 f1 = *reinterpret_cast<const float4*>((const char*)&Ab[cur][0] + ((Sb + 16) ^ sw));
            split8(f0, f1, ah[mi], al[mi]);
        }
        #pragma unroll
        for (int nf = 0; nf < 4; ++nf) {
            int col = wn * 64 + nf * 16 + cl;
            int Z = (col * 64 + rg * 16) ^ ((col & 7) << 4);
            bf16x8 bh = *reinterpret_cast<const bf16x8*>((const char*)&Bb[cur][0] + Z);
            bf16x8 bl = *reinterpret_cast<const bf16x8*>((const char*)&Bb[cur][0] + 8192 + Z);
            #pragma unroll
            for (int mi = 0; mi < 2; ++mi) {
                acc[mi][nf] = __builtin_amdgcn_mfma_f32_16x16x32_bf16(ah[mi], bh, acc[mi][nf], 0, 0, 0);
                acc[mi][nf] = __builtin_amdgcn_mfma_f32_16x16x32_bf16(al[mi], bh, acc[mi][nf], 0, 0, 0);
                acc[mi][nf] = __builtin_amdgcn_mfma_f32_16x16x32_bf16(ah[mi], bl, acc[mi][nf], 0, 0, 0);
            }
        }
        __syncthreads();
    }

    // C/D layout (measured m89): col = lane&15 within frag, row = (lane>>4)*4 + reg
    float* op = qhp + (size_t)ky * (BROWS * HDIM);
    #pragma unroll
    for (int mi = 0; mi < 2; ++mi) {
        int rowb = m0 + wm * 32 + mi * 16 + rg * 4;
        #pragma unroll
        for (int nf = 0; nf < 4; ++nf) {
            int col = wn * 64 + nf * 16 + cl;
            #pragma unroll
            for (int r = 0; r < 4; ++r)
                op[(size_t)(rowb + r) * HDIM + col] = acc[mi][nf][r];
        }
    }
}

// ---------- K4a: rel scores + fused top-10 -> idxA/wnA ----------
// grid 2048, block 256: 2 query-rows per block; thread owns (row g, segment n).
// 1 row x 128 h per thread; 8 blocks/CU (3 KB LDS, 28 VGPR) -> high occupancy.
__global__ __launch_bounds__(256)
void k_rel(const float* __restrict__ qhp,
           const float* __restrict__ shwT,
           const float* __restrict__ rw2,
           const float* __restrict__ rb2,
           const float* __restrict__ impA,
           const float* __restrict__ cA,
           int* __restrict__ idxA,
           float* __restrict__ wnA) {
    __shared__ float qs[2][HDIM];
    __shared__ float scL[2][128], wiL[2][128];
    int tid = threadIdx.x;
    int b0 = blockIdx.x * 2;
    int g = tid >> 7, n = tid & 127;

    {   // stage qs: thread (g, h=n) sums the split-k slices (ascending, same order)
        size_t o = (size_t)(b0 + g) * HDIM + n;
        float v = qhp[o];
        #pragma unroll
        for (int s = 1; s < KSLICES; ++s)
            v += qhp[(size_t)s * (BROWS * HDIM) + o];
        qs[g][n] = v;
    }
    __syncthreads();

    int nn = (n < NSEG) ? n : (NSEG - 1);   // clamp: lanes 100..127 duplicate, writes masked
    float a0 = 0.f;
    #pragma unroll 2
    for (int h = 0; h < HDIM; ++h) {
        float s = shwT[h * NSEG + nn];      // coalesced per-lane, L1-hot
        float w = rw2[h];                   // wave-uniform -> scalar load
        a0 = fmaf(gelu_f(qs[g][h] + s), w, a0);
    }
    if (n < NSEG) {
        float rel = 1.f / (1.f + expf(-(a0 + rb2[0])));
        scL[g][n] = cA[n] * rel;
        wiL[g][n] = impA[n] * rel;
    }
    __syncthreads();

    // fused top-k: wave 0 -> row 0, wave 1 -> row 1 (register-only butterfly)
    int w = tid >> 6, lane = tid & 63;
    if (w < 2) {
        int rr = w;
        float s1 = scL[rr][lane];
        float w1 = wiL[rr][lane];
        int i2 = lane + 64;
        float s2 = (i2 < NSEG) ? scL[rr][i2] : -1e30f;
        float w2 = (i2 < NSEG) ? wiL[rr][i2] : 0.f;

        float wv[TOPK]; int idxv[TOPK]; float wsum = 0.f;
        #pragma unroll
        for (int k = 0; k < TOPK; ++k) {
            float s; int i;
            if (s2 > s1) { s = s2; i = i2; } else { s = s1; i = lane; }
            #pragma unroll
            for (int off = 1; off < 64; off <<= 1) {
                float os = __shfl_xor(s, off);
                int oi = __shfl_xor(i, off);
                if (os > s || (os == s && oi < i)) { s = os; i = oi; }
            }
            float wi = __shfl((i < 64) ? w1 : w2, i & 63);
            idxv[k] = i; wv[k] = wi; wsum += wi;
            if (i == lane) s1 = -1e30f;
            if (i == i2)   s2 = -1e30f;
        }
        if (lane == 0) {
            int b = b0 + rr;
            float denom = wsum + 1e-8f;
            #pragma unroll
            for (int k = 0; k < TOPK; ++k) {
                idxA[b * TOPK + k] = idxv[k];
                wnA[b * TOPK + k]  = wv[k] / denom;
            }
        }
    }
}

// ---------- K4c: pure streaming gather: out = query + sum wn[k]*seg[idx[k]] ----------
// grid 4096, block 256. Weights/pointers via wave-uniform scalar loads; no LDS/barriers.
__global__ void k_gather(const float* __restrict__ query,
                         const float* __restrict__ seg,
                         const int* __restrict__ idxA,
                         const float* __restrict__ wnA,
                         float* __restrict__ out) {
    int b = blockIdx.x, tid = threadIdx.x;
    const int*   ip = idxA + b * TOPK;
    const float* wp = wnA  + b * TOPK;
    float wn[TOPK]; const float* srow[TOPK];
    #pragma unroll
    for (int k = 0; k < TOPK; ++k) {
        wn[k]   = wp[k];                          // uniform -> s_load
        srow[k] = seg + (size_t)ip[k] * DDIM;     // uniform -> s_load + sgpr addr
    }
    const float* qrow = query + (size_t)b * DDIM;
    float* orow = out + (size_t)b * DDIM;

    float4 q[4];
    #pragma unroll
    for (int c = 0; c < 4; ++c)
        q[c] = *reinterpret_cast<const float4*>(qrow + c * 1024 + tid * 4);
    #pragma unroll
    for (int k = 0; k < TOPK; ++k) {
        float4 s[4];
        #pragma unroll
        for (int c = 0; c < 4; ++c)
            s[c] = *reinterpret_cast<const float4*>(srow[k] + c * 1024 + tid * 4);
        #pragma unroll
        for (int c = 0; c < 4; ++c) {
            q[c].x = fmaf(wn[k], s[c].x, q[c].x);
            q[c].y = fmaf(wn[k], s[c].y, q[c].y);
            q[c].z = fmaf(wn[k], s[c].z, q[c].z);
            q[c].w = fmaf(wn[k], s[c].w, q[c].w);
        }
    }
    #pragma unroll
    for (int c = 0; c < 4; ++c)
        *reinterpret_cast<float4*>(orow + c * 1024 + tid * 4) = q[c];
}

extern "C" void kernel_launch(void* const* d_in, const int* in_sizes, int n_in,
                              void* d_out, int out_size, void* d_ws, size_t ws_size,
                              hipStream_t stream) {
    const float* query = (const float*)d_in[0];
    const float* seg   = (const float*)d_in[1];
    const int*   pos   = (const int*)d_in[2];
    const float* iw1   = (const float*)d_in[3];
    const float* ib1   = (const float*)d_in[4];
    const float* iw2   = (const float*)d_in[5];
    const float* ib2   = (const float*)d_in[6];
    const float* rw1   = (const float*)d_in[7];
    const float* rb1   = (const float*)d_in[8];
    const float* rw2   = (const float*)d_in[9];
    const float* rb2   = (const float*)d_in[10];
    float* out = (float*)d_out;

    char* ws = (char*)d_ws;
    // qhp (8 slices, 16 MiB) time-shares [0,16Mi) with segp (6.55 MB): segp dead
    // after k_seg_red; qhp written only by k_qh_mfma (stream-ordered).
    float* qhp  = (float*)(ws);                                   // 8*4096*128*4 = 16 MiB
    float* segp = (float*)(ws);                                   // 6.55 MB (dead before qhp)
    unsigned char* btI = (unsigned char*)(ws + 16 * 1024 * 1024); // 128 chunks * 16 KB = 2 MiB
    float* shwT = (float*)(ws + 18 * 1024 * 1024);                // 128*100*4 = 51.2 KB
    float* impA = (float*)(ws + 18 * 1024 * 1024 + 64 * 1024);
    float* cA   = (float*)(ws + 18 * 1024 * 1024 + 64 * 1024 + 4096);
    int*   idxA = (int*)  (ws + 18 * 1024 * 1024 + 128 * 1024);   // 160 KB
    float* wnA  = (float*)(ws + 18 * 1024 * 1024 + 320 * 1024);   // 160 KB

    hipLaunchKernelGGL(k_seg_gemm, dim3(25, 64), dim3(256), 0, stream, seg, iw1, rw1, segp);
    hipLaunchKernelGGL(k_seg_red, dim3(NSEG), dim3(256), 0, stream,
                       segp, pos, ib1, iw2, ib2, rb1, shwT, impA, cA);
    hipLaunchKernelGGL(k_bt, dim3(128), dim3(256), 0, stream, rw1, btI);
    hipLaunchKernelGGL(k_qh_mfma, dim3(64, KSLICES), dim3(256), 0, stream,
                       query, btI, qhp);
    hipLaunchKernelGGL(k_rel, dim3(BROWS / 2), dim3(256), 0, stream,
                       qhp, shwT, rw2, rb2, impA, cA, idxA, wnA);
    hipLaunchKernelGGL(k_gather, dim3(BROWS), dim3(256), 0, stream,
                       query, seg, idxA, wnA, out);
}

// Round 10
// 125.044 us; speedup vs baseline: 1.5050x; 1.0863x over previous
//
#include <hip/hip_runtime.h>
#include <math.h>

#define DDIM 4096
#define NSEG 100
#define HDIM 128
#define BROWS 4096
#define TOPK 10
#define KSLICES 8

typedef __attribute__((ext_vector_type(8))) short bf16x8;
typedef __attribute__((ext_vector_type(4))) float f32x4;

// async global->LDS, 16 B per lane; dest = uniform base + lane*16 (HW rule).
__device__ __forceinline__ void gl16(const void* g, void* l) {
    __builtin_amdgcn_global_load_lds(
        (const __attribute__((address_space(1))) unsigned int*)g,
        (__attribute__((address_space(3))) unsigned int*)l,
        16, 0, 0);
}

// Branch-free gelu: A&S 7.1.26 erf (abs err <= 1.5e-7), v_exp_f32 + v_rcp_f32.
__device__ __forceinline__ float gelu_f(float x) {
    float u  = x * 0.70710678118654752440f;
    float au = fminf(fabsf(u), 3.9f);                 // erf(3.9) == 1 to fp32
    float t  = __builtin_amdgcn_rcpf(fmaf(0.3275911f, au, 1.0f));
    float p  = fmaf(fmaf(fmaf(fmaf(1.061405429f, t, -1.453152027f), t,
                              1.421413741f), t, -0.284496736f), t, 0.254829592f) * t;
    float e  = __expf(-au * au);
    float er = fmaf(-p, e, 1.0f);                     // erf(|u|)
    er = copysignf(er, u);
    return 0.5f * x * (1.0f + er);
}

// Split fp32 -> bf16 hi (truncate) + bf16 lo (exact residual, truncated).
__device__ __forceinline__ void split8(const float4& a, const float4& b,
                                       bf16x8& hi, bf16x8& lo) {
    float v[8] = {a.x, a.y, a.z, a.w, b.x, b.y, b.z, b.w};
    uint hw[4], lw[4];
    #pragma unroll
    for (int j = 0; j < 4; ++j) {
        uint u0 = __float_as_uint(v[2 * j]);
        uint u1 = __float_as_uint(v[2 * j + 1]);
        hw[j] = (u0 >> 16) | (u1 & 0xffff0000u);
        float r0 = v[2 * j]     - __uint_as_float(u0 & 0xffff0000u);
        float r1 = v[2 * j + 1] - __uint_as_float(u1 & 0xffff0000u);
        lw[j] = (__float_as_uint(r0) >> 16) | (__float_as_uint(r1) & 0xffff0000u);
    }
    uint4 h = make_uint4(hw[0], hw[1], hw[2], hw[3]);
    uint4 l = make_uint4(lw[0], lw[1], lw[2], lw[3]);
    hi = __builtin_bit_cast(bf16x8, h);
    lo = __builtin_bit_cast(bf16x8, l);
}

// ---------- K_front: seg_gemm (blocks 0..1599) || bt (blocks 1600..1727) ----------
// seg_gemm: segp[ks][n][col] partials, grid-equiv (25,64), block 256.
// bt: rw1[:D] -> per-K-chunk pre-swizzled LDS images (byte Z = (col*64+u*16)^((col&7)<<4)).
__global__ void k_front(const float* __restrict__ seg,
                        const float* __restrict__ iw1,
                        const float* __restrict__ rw1,
                        float* __restrict__ segp,
                        unsigned char* __restrict__ btI) {
    __shared__ __align__(16) float shf[32 * 129];   // 16.5 KB, union for both parts
    int bid = blockIdx.x, tid = threadIdx.x;
    if (bid < 1600) {
        float (*segT)[5] = reinterpret_cast<float (*)[5]>(shf);
        int ng = bid % 25;
        int ks = (bid / 25) * 64;
        {
            int k = tid & 63, j = tid >> 6;
            segT[k][j] = seg[(size_t)(ng * 4 + j) * DDIM + ks + k];
        }
        __syncthreads();
        int col = tid;
        float a0 = 0.f, a1 = 0.f, a2 = 0.f, a3 = 0.f;
        const float* w = (col < HDIM) ? (iw1 + col)
                                      : (rw1 + (size_t)DDIM * HDIM + (col - HDIM));
        #pragma unroll 8
        for (int k = 0; k < 64; ++k) {
            float wv = w[(size_t)(ks + k) * HDIM];
            a0 = fmaf(segT[k][0], wv, a0);
            a1 = fmaf(segT[k][1], wv, a1);
            a2 = fmaf(segT[k][2], wv, a2);
            a3 = fmaf(segT[k][3], wv, a3);
        }
        float* outp = segp + (size_t)(bid / 25) * (NSEG * 256) + (size_t)(ng * 4) * 256 + col;
        outp[0] = a0; outp[256] = a1; outp[512] = a2; outp[768] = a3;
    } else {
        float (*tile)[129] = reinterpret_cast<float (*)[129]>(shf);
        int c = bid - 1600;
        #pragma unroll
        for (int i = 0; i < 4; ++i) {
            int e = i * 1024 + tid * 4;
            int k = e >> 7, n = e & 127;
            *reinterpret_cast<float4*>(&tile[k][n]) =
                *reinterpret_cast<const float4*>(rw1 + (size_t)(c * 32 + k) * HDIM + n);
        }
        __syncthreads();
        unsigned char* img = btI + (size_t)c * 16384;
        #pragma unroll
        for (int uu = 0; uu < 2; ++uu) {
            int U = tid * 2 + uu;            // 0..511
            int col = U >> 2;
            int u = U & 3;
            int Z = (col * 64 + u * 16) ^ ((col & 7) << 4);
            uint hw[4], lw[4];
            #pragma unroll
            for (int j = 0; j < 4; ++j) {
                float x0 = tile[u * 8 + 2 * j][col];
                float x1 = tile[u * 8 + 2 * j + 1][col];
                uint u0 = __float_as_uint(x0), u1 = __float_as_uint(x1);
                hw[j] = (u0 >> 16) | (u1 & 0xffff0000u);
                float r0 = x0 - __uint_as_float(u0 & 0xffff0000u);
                float r1 = x1 - __uint_as_float(u1 & 0xffff0000u);
                lw[j] = (__float_as_uint(r0) >> 16) | (__float_as_uint(r1) & 0xffff0000u);
            }
            *reinterpret_cast<uint4*>(img + Z)        = make_uint4(hw[0], hw[1], hw[2], hw[3]);
            *reinterpret_cast<uint4*>(img + 8192 + Z) = make_uint4(lw[0], lw[1], lw[2], lw[3]);
        }
    }
}

// ---------- K_mid: qh_mfma (blocks 0..511) || seg_red (blocks 512..611) ----------
// qh: m97-style global_load_lds double-buffer, 64 rows x 128 cols x K=512 per block.
// seg_red: reduce segp -> importance/coeff/shwT.
__global__ __launch_bounds__(256)
void k_mid(const float* __restrict__ query,
           const unsigned char* __restrict__ btI,
           float* __restrict__ qhp,
           const float* __restrict__ segp,
           const int* __restrict__ positions,
           const float* __restrict__ ib1,
           const float* __restrict__ iw2,
           const float* __restrict__ ib2,
           const float* __restrict__ rb1,
           float* __restrict__ shwT, float* __restrict__ impA,
           float* __restrict__ cA) {
    __shared__ __align__(16) char lds[49152];       // qh: Ab 16K | Bb 32K; seg_red: red 512B
    int bid = blockIdx.x, tid = threadIdx.x;
    if (bid < 512) {
        float  (*Ab)[2048] = reinterpret_cast<float (*)[2048]>(lds);
        ushort (*Bb)[8192] = reinterpret_cast<ushort (*)[8192]>(lds + 16384);
        int lane = tid & 63, w = tid >> 6;
        int cl = lane & 15, rg = lane >> 4;
        int wm = w >> 1, wn = w & 1;       // wave quadrant: 32 rows x 64 cols
        int m0 = (bid & 63) * 64;
        int ky = bid >> 6;
        int k0 = ky * 512;

        const float* aSrc0;
        const float* aSrc1;
        {
            int X0 = w * 2048 + lane * 16;
            int r0_ = X0 >> 7, kb0 = (X0 & 127) ^ ((r0_ & 7) << 4);
            aSrc0 = query + (size_t)(m0 + r0_) * DDIM + k0 + (kb0 >> 2);
            int X1 = X0 + 1024;
            int r1_ = X1 >> 7, kb1 = (X1 & 127) ^ ((r1_ & 7) << 4);
            aSrc1 = query + (size_t)(m0 + r1_) * DDIM + k0 + (kb1 >> 2);
        }
        const unsigned char* bSrc = btI + (size_t)(ky * 16) * 16384 + w * 4096 + lane * 16;

        f32x4 acc[2][4];
        #pragma unroll
        for (int mi = 0; mi < 2; ++mi)
            #pragma unroll
            for (int nf = 0; nf < 4; ++nf) acc[mi][nf] = (f32x4)0.f;

        {
            char* ad = (char*)&Ab[0][0] + w * 2048;
            char* bd = (char*)&Bb[0][0] + w * 4096;
            gl16(aSrc0, ad);
            gl16(aSrc1, ad + 1024);
            #pragma unroll
            for (int j = 0; j < 4; ++j) gl16(bSrc + j * 1024, bd + j * 1024);
        }
        __syncthreads();

        #pragma unroll 2
        for (int t = 0; t < 16; ++t) {
            int cur = t & 1;
            if (t < 15) {
                char* ad = (char*)&Ab[cur ^ 1][0] + w * 2048;
                char* bd = (char*)&Bb[cur ^ 1][0] + w * 4096;
                gl16(aSrc0 + (t + 1) * 32, ad);
                gl16(aSrc1 + (t + 1) * 32, ad + 1024);
                const unsigned char* bs = bSrc + (size_t)(t + 1) * 16384;
                #pragma unroll
                for (int j = 0; j < 4; ++j) gl16(bs + j * 1024, bd + j * 1024);
            }
            bf16x8 ah[2], al[2];
            #pragma unroll
            for (int mi = 0; mi < 2; ++mi) {
                int row = wm * 32 + mi * 16 + cl;
                int sw = (row & 7) << 4;
                int Sb = row * 128 + rg * 32;
                float4 f0 = *reinterpret_cast<const float4*>((const char*)&Ab[cur][0] + (Sb ^ sw));
                float4 f1 = *reinterpret_cast<const float4*>((const char*)&Ab[cur][0] + ((Sb + 16) ^ sw));
                split8(f0, f1, ah[mi], al[mi]);
            }
            #pragma unroll
            for (int nf = 0; nf < 4; ++nf) {
                int col = wn * 64 + nf * 16 + cl;
                int Z = (col * 64 + rg * 16) ^ ((col & 7) << 4);
                // buffer layout: {hi 0..8191 | lo 8192..16383} BYTES within Bb[cur]
                bf16x8 bh = *reinterpret_cast<const bf16x8*>((const char*)&Bb[cur][0] + Z);
                bf16x8 bl = *reinterpret_cast<const bf16x8*>((const char*)&Bb[cur][0] + 8192 + Z);
                #pragma unroll
                for (int mi = 0; mi < 2; ++mi) {
                    acc[mi][nf] = __builtin_amdgcn_mfma_f32_16x16x32_bf16(ah[mi], bh, acc[mi][nf], 0, 0, 0);
                    acc[mi][nf] = __builtin_amdgcn_mfma_f32_16x16x32_bf16(al[mi], bh, acc[mi][nf], 0, 0, 0);
                    acc[mi][nf] = __builtin_amdgcn_mfma_f32_16x16x32_bf16(ah[mi], bl, acc[mi][nf], 0, 0, 0);
                }
            }
            __syncthreads();
        }

        float* op = qhp + (size_t)ky * (BROWS * HDIM);
        #pragma unroll
        for (int mi = 0; mi < 2; ++mi) {
            int rowb = m0 + wm * 32 + mi * 16 + rg * 4;
            #pragma unroll
            for (int nf = 0; nf < 4; ++nf) {
                int col = wn * 64 + nf * 16 + cl;
                #pragma unroll
                for (int r = 0; r < 4; ++r)
                    op[(size_t)(rowb + r) * HDIM + col] = acc[mi][nf][r];
            }
        }
    } else {
        float* red = reinterpret_cast<float*>(lds);
        int n = bid - 512;
        float v = 0.f;
        #pragma unroll
        for (int s = 0; s < 64; ++s)
            v += segp[(size_t)s * (NSEG * 256) + (size_t)n * 256 + tid];
        if (tid < HDIM) {
            red[tid] = gelu_f(v + ib1[tid]) * iw2[tid];
        } else {
            shwT[(size_t)(tid - HDIM) * NSEG + n] = v + rb1[tid - HDIM];
        }
        __syncthreads();
        if (tid == 0) {
            float s = 0.f;
            for (int j = 0; j < HDIM; ++j) s += red[j];
            float imp = 1.f / (1.f + expf(-(s + ib2[0])));
            float pf = powf(0.95f, (float)NSEG - (float)positions[n] - 1.0f);
            impA[n] = imp;
            cA[n] = imp * (0.5f + 0.5f * pf);
        }
    }
}

// ---------- K_relg: rel + top-10 + gather, fused ----------
// grid 2048, block 256: 2 query-rows per block. Rel is VALU-bound, gather is
// HBM-bound -> cross-block overlap of complementary pipes.
__global__ __launch_bounds__(256)
void k_relg(const float* __restrict__ qhp,
            const float* __restrict__ shwT,
            const float* __restrict__ rw2,
            const float* __restrict__ rb2,
            const float* __restrict__ impA,
            const float* __restrict__ cA,
            const float* __restrict__ query,
            const float* __restrict__ seg,
            float* __restrict__ out) {
    __shared__ float qs[2][HDIM];
    __shared__ float scL[2][128], wiL[2][128];
    __shared__ float wnS[2][TOPK];
    __shared__ int   idxS[2][TOPK];
    int tid = threadIdx.x;
    int b0 = blockIdx.x * 2;
    int g = tid >> 7, n = tid & 127;

    {   // stage qs: thread (g, h=n) sums the split-k slices (ascending, same order)
        size_t o = (size_t)(b0 + g) * HDIM + n;
        float v = qhp[o];
        #pragma unroll
        for (int s = 1; s < KSLICES; ++s)
            v += qhp[(size_t)s * (BROWS * HDIM) + o];
        qs[g][n] = v;
    }
    __syncthreads();

    int nn = (n < NSEG) ? n : (NSEG - 1);   // clamp: lanes 100..127 duplicate, writes masked
    float a0 = 0.f;
    #pragma unroll 2
    for (int h = 0; h < HDIM; ++h) {
        float s = shwT[h * NSEG + nn];      // coalesced per-lane, L1-hot
        float w = rw2[h];                   // wave-uniform -> scalar load
        a0 = fmaf(gelu_f(qs[g][h] + s), w, a0);
    }
    if (n < NSEG) {
        float rel = 1.f / (1.f + expf(-(a0 + rb2[0])));
        scL[g][n] = cA[n] * rel;
        wiL[g][n] = impA[n] * rel;
    }
    __syncthreads();

    // top-k: wave 0 -> row 0, wave 1 -> row 1 (register-only butterfly)
    int w = tid >> 6, lane = tid & 63;
    if (w < 2) {
        int rr = w;
        float s1 = scL[rr][lane];
        float w1 = wiL[rr][lane];
        int i2 = lane + 64;
        float s2 = (i2 < NSEG) ? scL[rr][i2] : -1e30f;
        float w2 = (i2 < NSEG) ? wiL[rr][i2] : 0.f;

        float wv[TOPK]; int idxv[TOPK]; float wsum = 0.f;
        #pragma unroll
        for (int k = 0; k < TOPK; ++k) {
            float s; int i;
            if (s2 > s1) { s = s2; i = i2; } else { s = s1; i = lane; }
            #pragma unroll
            for (int off = 1; off < 64; off <<= 1) {
                float os = __shfl_xor(s, off);
                int oi = __shfl_xor(i, off);
                if (os > s || (os == s && oi < i)) { s = os; i = oi; }
            }
            float wi = __shfl((i < 64) ? w1 : w2, i & 63);
            idxv[k] = i; wv[k] = wi; wsum += wi;
            if (i == lane) s1 = -1e30f;
            if (i == i2)   s2 = -1e30f;
        }
        if (lane == 0) {
            float denom = wsum + 1e-8f;
            #pragma unroll
            for (int k = 0; k < TOPK; ++k) {
                idxS[rr][k] = idxv[k];
                wnS[rr][k]  = wv[k] / denom;
            }
        }
    }
    __syncthreads();

    // gather: both rows, all 256 threads; same math/order as the old k_gather
    #pragma unroll
    for (int r = 0; r < 2; ++r) {
        int b = b0 + r;
        float wn_[TOPK]; const float* srow[TOPK];
        #pragma unroll
        for (int k = 0; k < TOPK; ++k) {
            wn_[k]  = wnS[r][k];
            srow[k] = seg + (size_t)idxS[r][k] * DDIM;
        }
        const float* qrow = query + (size_t)b * DDIM;
        float* orow = out + (size_t)b * DDIM;
        #pragma unroll
        for (int c = 0; c < 4; ++c) {
            int d0 = c * 1024 + tid * 4;
            float4 q4 = *reinterpret_cast<const float4*>(qrow + d0);
            #pragma unroll
            for (int k = 0; k < TOPK; ++k) {
                float4 s4 = *reinterpret_cast<const float4*>(srow[k] + d0);
                q4.x = fmaf(wn_[k], s4.x, q4.x);
                q4.y = fmaf(wn_[k], s4.y, q4.y);
                q4.z = fmaf(wn_[k], s4.z, q4.z);
                q4.w = fmaf(wn_[k], s4.w, q4.w);
            }
            *reinterpret_cast<float4*>(orow + d0) = q4;
        }
    }
}

extern "C" void kernel_launch(void* const* d_in, const int* in_sizes, int n_in,
                              void* d_out, int out_size, void* d_ws, size_t ws_size,
                              hipStream_t stream) {
    const float* query = (const float*)d_in[0];
    const float* seg   = (const float*)d_in[1];
    const int*   pos   = (const int*)d_in[2];
    const float* iw1   = (const float*)d_in[3];
    const float* ib1   = (const float*)d_in[4];
    const float* iw2   = (const float*)d_in[5];
    const float* ib2   = (const float*)d_in[6];
    const float* rw1   = (const float*)d_in[7];
    const float* rb1   = (const float*)d_in[8];
    const float* rw2   = (const float*)d_in[9];
    const float* rb2   = (const float*)d_in[10];
    float* out = (float*)d_out;

    char* ws = (char*)d_ws;
    // qhp written by k_mid's qh blocks while seg_red blocks read segp -> keep
    // them in SEPARATE regions (they are live in the same launch).
    float* qhp  = (float*)(ws);                                   // 16 MiB
    float* segp = (float*)(ws + 16 * 1024 * 1024);                // 6.55 MiB
    unsigned char* btI = (unsigned char*)(ws + 23 * 1024 * 1024); // 2 MiB
    float* shwT = (float*)(ws + 25 * 1024 * 1024);                // 51.2 KB
    float* impA = (float*)(ws + 25 * 1024 * 1024 + 64 * 1024);
    float* cA   = (float*)(ws + 25 * 1024 * 1024 + 64 * 1024 + 4096);

    hipLaunchKernelGGL(k_front, dim3(1728), dim3(256), 0, stream,
                       seg, iw1, rw1, segp, btI);
    hipLaunchKernelGGL(k_mid, dim3(612), dim3(256), 0, stream,
                       query, btI, qhp, segp, pos, ib1, iw2, ib2, rb1,
                       shwT, impA, cA);
    hipLaunchKernelGGL(k_relg, dim3(BROWS / 2), dim3(256), 0, stream,
                       qhp, shwT, rw2, rb2, impA, cA, query, seg, out);
}

// Round 11
// 115.324 us; speedup vs baseline: 1.6318x; 1.0843x over previous
//
#include <hip/hip_runtime.h>
#include <math.h>

#define DDIM 4096
#define NSEG 100
#define HDIM 128
#define BROWS 4096
#define TOPK 10
#define KSLICES 8

typedef __attribute__((ext_vector_type(8))) short bf16x8;
typedef __attribute__((ext_vector_type(4))) float f32x4;

// async global->LDS, 16 B per lane; dest = uniform base + lane*16 (HW rule).
__device__ __forceinline__ void gl16(const void* g, void* l) {
    __builtin_amdgcn_global_load_lds(
        (const __attribute__((address_space(1))) unsigned int*)g,
        (__attribute__((address_space(3))) unsigned int*)l,
        16, 0, 0);
}

// Branch-free gelu: A&S 7.1.26 erf (abs err <= 1.5e-7), v_exp_f32 + v_rcp_f32.
__device__ __forceinline__ float gelu_f(float x) {
    float u  = x * 0.70710678118654752440f;
    float au = fminf(fabsf(u), 3.9f);                 // erf(3.9) == 1 to fp32
    float t  = __builtin_amdgcn_rcpf(fmaf(0.3275911f, au, 1.0f));
    float p  = fmaf(fmaf(fmaf(fmaf(1.061405429f, t, -1.453152027f), t,
                              1.421413741f), t, -0.284496736f), t, 0.254829592f) * t;
    float e  = __expf(-au * au);
    float er = fmaf(-p, e, 1.0f);                     // erf(|u|)
    er = copysignf(er, u);
    return 0.5f * x * (1.0f + er);
}

// Split fp32 -> bf16 hi (truncate) + bf16 lo (exact residual, truncated).
__device__ __forceinline__ void split8(const float4& a, const float4& b,
                                       bf16x8& hi, bf16x8& lo) {
    float v[8] = {a.x, a.y, a.z, a.w, b.x, b.y, b.z, b.w};
    uint hw[4], lw[4];
    #pragma unroll
    for (int j = 0; j < 4; ++j) {
        uint u0 = __float_as_uint(v[2 * j]);
        uint u1 = __float_as_uint(v[2 * j + 1]);
        hw[j] = (u0 >> 16) | (u1 & 0xffff0000u);
        float r0 = v[2 * j]     - __uint_as_float(u0 & 0xffff0000u);
        float r1 = v[2 * j + 1] - __uint_as_float(u1 & 0xffff0000u);
        lw[j] = (__float_as_uint(r0) >> 16) | (__float_as_uint(r1) & 0xffff0000u);
    }
    uint4 h = make_uint4(hw[0], hw[1], hw[2], hw[3]);
    uint4 l = make_uint4(lw[0], lw[1], lw[2], lw[3]);
    hi = __builtin_bit_cast(bf16x8, h);
    lo = __builtin_bit_cast(bf16x8, l);
}

// ---------- K_front: seg_gemm (blocks 0..1599) || bt (blocks 1600..1727) ----------
// seg_gemm: segp[ks][n][col] partials, grid-equiv (25,64), block 256.
// bt: rw1[:D] -> per-K-chunk pre-swizzled LDS images (byte Z = (col*64+u*16)^((col&7)<<4)).
__global__ void k_front(const float* __restrict__ seg,
                        const float* __restrict__ iw1,
                        const float* __restrict__ rw1,
                        float* __restrict__ segp,
                        unsigned char* __restrict__ btI) {
    __shared__ __align__(16) float shf[32 * 129];   // 16.5 KB, union for both parts
    int bid = blockIdx.x, tid = threadIdx.x;
    if (bid < 1600) {
        float (*segT)[5] = reinterpret_cast<float (*)[5]>(shf);
        int ng = bid % 25;
        int ks = (bid / 25) * 64;
        {
            int k = tid & 63, j = tid >> 6;
            segT[k][j] = seg[(size_t)(ng * 4 + j) * DDIM + ks + k];
        }
        __syncthreads();
        int col = tid;
        float a0 = 0.f, a1 = 0.f, a2 = 0.f, a3 = 0.f;
        const float* w = (col < HDIM) ? (iw1 + col)
                                      : (rw1 + (size_t)DDIM * HDIM + (col - HDIM));
        #pragma unroll 8
        for (int k = 0; k < 64; ++k) {
            float wv = w[(size_t)(ks + k) * HDIM];
            a0 = fmaf(segT[k][0], wv, a0);
            a1 = fmaf(segT[k][1], wv, a1);
            a2 = fmaf(segT[k][2], wv, a2);
            a3 = fmaf(segT[k][3], wv, a3);
        }
        float* outp = segp + (size_t)(bid / 25) * (NSEG * 256) + (size_t)(ng * 4) * 256 + col;
        outp[0] = a0; outp[256] = a1; outp[512] = a2; outp[768] = a3;
    } else {
        float (*tile)[129] = reinterpret_cast<float (*)[129]>(shf);
        int c = bid - 1600;
        #pragma unroll
        for (int i = 0; i < 4; ++i) {
            int e = i * 1024 + tid * 4;
            int k = e >> 7, n = e & 127;
            *reinterpret_cast<float4*>(&tile[k][n]) =
                *reinterpret_cast<const float4*>(rw1 + (size_t)(c * 32 + k) * HDIM + n);
        }
        __syncthreads();
        unsigned char* img = btI + (size_t)c * 16384;
        #pragma unroll
        for (int uu = 0; uu < 2; ++uu) {
            int U = tid * 2 + uu;            // 0..511
            int col = U >> 2;
            int u = U & 3;
            int Z = (col * 64 + u * 16) ^ ((col & 7) << 4);
            uint hw[4], lw[4];
            #pragma unroll
            for (int j = 0; j < 4; ++j) {
                float x0 = tile[u * 8 + 2 * j][col];
                float x1 = tile[u * 8 + 2 * j + 1][col];
                uint u0 = __float_as_uint(x0), u1 = __float_as_uint(x1);
                hw[j] = (u0 >> 16) | (u1 & 0xffff0000u);
                float r0 = x0 - __uint_as_float(u0 & 0xffff0000u);
                float r1 = x1 - __uint_as_float(u1 & 0xffff0000u);
                lw[j] = (__float_as_uint(r0) >> 16) | (__float_as_uint(r1) & 0xffff0000u);
            }
            *reinterpret_cast<uint4*>(img + Z)        = make_uint4(hw[0], hw[1], hw[2], hw[3]);
            *reinterpret_cast<uint4*>(img + 8192 + Z) = make_uint4(lw[0], lw[1], lw[2], lw[3]);
        }
    }
}

// ---------- K_mid: qh_mfma (blocks 0..511) || seg_red (blocks 512..611) ----------
// qh: m97-style global_load_lds double-buffer, 64 rows x 128 cols x K=512 per block.
// seg_red: reduce segp -> importance/coeff/shwT.
__global__ __launch_bounds__(256)
void k_mid(const float* __restrict__ query,
           const unsigned char* __restrict__ btI,
           float* __restrict__ qhp,
           const float* __restrict__ segp,
           const int* __restrict__ positions,
           const float* __restrict__ ib1,
           const float* __restrict__ iw2,
           const float* __restrict__ ib2,
           const float* __restrict__ rb1,
           float* __restrict__ shwT, float* __restrict__ impA,
           float* __restrict__ cA) {
    __shared__ __align__(16) char lds[49152];       // qh: Ab 16K | Bb 32K; seg_red: red 512B
    int bid = blockIdx.x, tid = threadIdx.x;
    if (bid < 512) {
        float  (*Ab)[2048] = reinterpret_cast<float (*)[2048]>(lds);
        ushort (*Bb)[8192] = reinterpret_cast<ushort (*)[8192]>(lds + 16384);
        int lane = tid & 63, w = tid >> 6;
        int cl = lane & 15, rg = lane >> 4;
        int wm = w >> 1, wn = w & 1;       // wave quadrant: 32 rows x 64 cols
        int m0 = (bid & 63) * 64;
        int ky = bid >> 6;
        int k0 = ky * 512;

        const float* aSrc0;
        const float* aSrc1;
        {
            int X0 = w * 2048 + lane * 16;
            int r0_ = X0 >> 7, kb0 = (X0 & 127) ^ ((r0_ & 7) << 4);
            aSrc0 = query + (size_t)(m0 + r0_) * DDIM + k0 + (kb0 >> 2);
            int X1 = X0 + 1024;
            int r1_ = X1 >> 7, kb1 = (X1 & 127) ^ ((r1_ & 7) << 4);
            aSrc1 = query + (size_t)(m0 + r1_) * DDIM + k0 + (kb1 >> 2);
        }
        const unsigned char* bSrc = btI + (size_t)(ky * 16) * 16384 + w * 4096 + lane * 16;

        f32x4 acc[2][4];
        #pragma unroll
        for (int mi = 0; mi < 2; ++mi)
            #pragma unroll
            for (int nf = 0; nf < 4; ++nf) acc[mi][nf] = (f32x4)0.f;

        {
            char* ad = (char*)&Ab[0][0] + w * 2048;
            char* bd = (char*)&Bb[0][0] + w * 4096;
            gl16(aSrc0, ad);
            gl16(aSrc1, ad + 1024);
            #pragma unroll
            for (int j = 0; j < 4; ++j) gl16(bSrc + j * 1024, bd + j * 1024);
        }
        __syncthreads();

        #pragma unroll 2
        for (int t = 0; t < 16; ++t) {
            int cur = t & 1;
            if (t < 15) {
                char* ad = (char*)&Ab[cur ^ 1][0] + w * 2048;
                char* bd = (char*)&Bb[cur ^ 1][0] + w * 4096;
                gl16(aSrc0 + (t + 1) * 32, ad);
                gl16(aSrc1 + (t + 1) * 32, ad + 1024);
                const unsigned char* bs = bSrc + (size_t)(t + 1) * 16384;
                #pragma unroll
                for (int j = 0; j < 4; ++j) gl16(bs + j * 1024, bd + j * 1024);
            }
            bf16x8 ah[2], al[2];
            #pragma unroll
            for (int mi = 0; mi < 2; ++mi) {
                int row = wm * 32 + mi * 16 + cl;
                int sw = (row & 7) << 4;
                int Sb = row * 128 + rg * 32;
                float4 f0 = *reinterpret_cast<const float4*>((const char*)&Ab[cur][0] + (Sb ^ sw));
                float4 f1 = *reinterpret_cast<const float4*>((const char*)&Ab[cur][0] + ((Sb + 16) ^ sw));
                split8(f0, f1, ah[mi], al[mi]);
            }
            #pragma unroll
            for (int nf = 0; nf < 4; ++nf) {
                int col = wn * 64 + nf * 16 + cl;
                int Z = (col * 64 + rg * 16) ^ ((col & 7) << 4);
                // buffer layout: {hi 0..8191 | lo 8192..16383} BYTES within Bb[cur]
                bf16x8 bh = *reinterpret_cast<const bf16x8*>((const char*)&Bb[cur][0] + Z);
                bf16x8 bl = *reinterpret_cast<const bf16x8*>((const char*)&Bb[cur][0] + 8192 + Z);
                #pragma unroll
                for (int mi = 0; mi < 2; ++mi) {
                    acc[mi][nf] = __builtin_amdgcn_mfma_f32_16x16x32_bf16(ah[mi], bh, acc[mi][nf], 0, 0, 0);
                    acc[mi][nf] = __builtin_amdgcn_mfma_f32_16x16x32_bf16(al[mi], bh, acc[mi][nf], 0, 0, 0);
                    acc[mi][nf] = __builtin_amdgcn_mfma_f32_16x16x32_bf16(ah[mi], bl, acc[mi][nf], 0, 0, 0);
                }
            }
            __syncthreads();
        }

        float* op = qhp + (size_t)ky * (BROWS * HDIM);
        #pragma unroll
        for (int mi = 0; mi < 2; ++mi) {
            int rowb = m0 + wm * 32 + mi * 16 + rg * 4;
            #pragma unroll
            for (int nf = 0; nf < 4; ++nf) {
                int col = wn * 64 + nf * 16 + cl;
                #pragma unroll
                for (int r = 0; r < 4; ++r)
                    op[(size_t)(rowb + r) * HDIM + col] = acc[mi][nf][r];
            }
        }
    } else {
        float* red = reinterpret_cast<float*>(lds);
        int n = bid - 512;
        float v = 0.f;
        #pragma unroll
        for (int s = 0; s < 64; ++s)
            v += segp[(size_t)s * (NSEG * 256) + (size_t)n * 256 + tid];
        if (tid < HDIM) {
            red[tid] = gelu_f(v + ib1[tid]) * iw2[tid];
        } else {
            shwT[(size_t)(tid - HDIM) * NSEG + n] = v + rb1[tid - HDIM];
        }
        __syncthreads();
        if (tid == 0) {
            float s = 0.f;
            for (int j = 0; j < HDIM; ++j) s += red[j];
            float imp = 1.f / (1.f + expf(-(s + ib2[0])));
            float pf = powf(0.95f, (float)NSEG - (float)positions[n] - 1.0f);
            impA[n] = imp;
            cA[n] = imp * (0.5f + 0.5f * pf);
        }
    }
}

// ---------- K4a: rel scores + top-10 -> idxA/wnA ----------
// grid 1024, block 256: 4 query-rows per block, 2 rows/thread (amortizes shwT
// load + loop overhead); LDS 6 KB, high occupancy. Top-k: wave w -> row w.
__global__ __launch_bounds__(256)
void k_rel(const float* __restrict__ qhp,
           const float* __restrict__ shwT,
           const float* __restrict__ rw2,
           const float* __restrict__ rb2,
           const float* __restrict__ impA,
           const float* __restrict__ cA,
           int* __restrict__ idxA,
           float* __restrict__ wnA) {
    __shared__ float qs[4][HDIM];
    __shared__ float scL[4][128], wiL[4][128];
    int tid = threadIdx.x;
    int b0 = blockIdx.x * 4;

    // stage qs: 4 rows x 128 h = 512 sums; thread stages idx = tid, tid+256
    #pragma unroll
    for (int i = 0; i < 2; ++i) {
        int idx = tid + i * 256;
        int r = idx >> 7, h = idx & 127;
        size_t o = (size_t)(b0 + r) * HDIM + h;
        float v = qhp[o];
        #pragma unroll
        for (int s = 1; s < KSLICES; ++s)
            v += qhp[(size_t)s * (BROWS * HDIM) + o];
        qs[r][h] = v;
    }
    __syncthreads();

    int g = tid >> 7, n = tid & 127;        // thread owns rows 2g, 2g+1, segment n
    int nn = (n < NSEG) ? n : (NSEG - 1);   // clamp: lanes 100..127 duplicate, masked
    int r0 = g * 2;
    float a0 = 0.f, a1 = 0.f;
    #pragma unroll 2
    for (int h = 0; h < HDIM; ++h) {
        float s = shwT[h * NSEG + nn];      // coalesced per-lane, L1-hot
        float w = rw2[h];                   // wave-uniform -> scalar load
        a0 = fmaf(gelu_f(qs[r0 + 0][h] + s), w, a0);
        a1 = fmaf(gelu_f(qs[r0 + 1][h] + s), w, a1);
    }
    if (n < NSEG) {
        float rb2f = rb2[0];
        float ca = cA[n], ia = impA[n];
        float rel0 = 1.f / (1.f + expf(-(a0 + rb2f)));
        float rel1 = 1.f / (1.f + expf(-(a1 + rb2f)));
        scL[r0 + 0][n] = ca * rel0;  wiL[r0 + 0][n] = ia * rel0;
        scL[r0 + 1][n] = ca * rel1;  wiL[r0 + 1][n] = ia * rel1;
    }
    __syncthreads();

    // top-k: wave w -> row w (register-only butterfly, identical to proven r8)
    int w = tid >> 6, lane = tid & 63;
    {
        int rr = w;
        float s1 = scL[rr][lane];
        float w1 = wiL[rr][lane];
        int i2 = lane + 64;
        float s2 = (i2 < NSEG) ? scL[rr][i2] : -1e30f;
        float w2 = (i2 < NSEG) ? wiL[rr][i2] : 0.f;

        float wv[TOPK]; int idxv[TOPK]; float wsum = 0.f;
        #pragma unroll
        for (int k = 0; k < TOPK; ++k) {
            float s; int i;
            if (s2 > s1) { s = s2; i = i2; } else { s = s1; i = lane; }
            #pragma unroll
            for (int off = 1; off < 64; off <<= 1) {
                float os = __shfl_xor(s, off);
                int oi = __shfl_xor(i, off);
                if (os > s || (os == s && oi < i)) { s = os; i = oi; }
            }
            float wi = __shfl((i < 64) ? w1 : w2, i & 63);
            idxv[k] = i; wv[k] = wi; wsum += wi;
            if (i == lane) s1 = -1e30f;
            if (i == i2)   s2 = -1e30f;
        }
        if (lane == 0) {
            int b = b0 + rr;
            float denom = wsum + 1e-8f;
            #pragma unroll
            for (int k = 0; k < TOPK; ++k) {
                idxA[b * TOPK + k] = idxv[k];
                wnA[b * TOPK + k]  = wv[k] / denom;
            }
        }
    }
}

// ---------- K4c: pure streaming gather: out = query + sum wn[k]*seg[idx[k]] ----------
// grid 4096, block 256. Weights/pointers via wave-uniform scalar loads; no LDS/barriers.
__global__ void k_gather(const float* __restrict__ query,
                         const float* __restrict__ seg,
                         const int* __restrict__ idxA,
                         const float* __restrict__ wnA,
                         float* __restrict__ out) {
    int b = blockIdx.x, tid = threadIdx.x;
    const int*   ip = idxA + b * TOPK;
    const float* wp = wnA  + b * TOPK;
    float wn[TOPK]; const float* srow[TOPK];
    #pragma unroll
    for (int k = 0; k < TOPK; ++k) {
        wn[k]   = wp[k];                          // uniform -> s_load
        srow[k] = seg + (size_t)ip[k] * DDIM;     // uniform -> s_load + sgpr addr
    }
    const float* qrow = query + (size_t)b * DDIM;
    float* orow = out + (size_t)b * DDIM;

    float4 q[4];
    #pragma unroll
    for (int c = 0; c < 4; ++c)
        q[c] = *reinterpret_cast<const float4*>(qrow + c * 1024 + tid * 4);
    #pragma unroll
    for (int k = 0; k < TOPK; ++k) {
        float4 s[4];
        #pragma unroll
        for (int c = 0; c < 4; ++c)
            s[c] = *reinterpret_cast<const float4*>(srow[k] + c * 1024 + tid * 4);
        #pragma unroll
        for (int c = 0; c < 4; ++c) {
            q[c].x = fmaf(wn[k], s[c].x, q[c].x);
            q[c].y = fmaf(wn[k], s[c].y, q[c].y);
            q[c].z = fmaf(wn[k], s[c].z, q[c].z);
            q[c].w = fmaf(wn[k], s[c].w, q[c].w);
        }
    }
    #pragma unroll
    for (int c = 0; c < 4; ++c)
        *reinterpret_cast<float4*>(orow + c * 1024 + tid * 4) = q[c];
}

extern "C" void kernel_launch(void* const* d_in, const int* in_sizes, int n_in,
                              void* d_out, int out_size, void* d_ws, size_t ws_size,
                              hipStream_t stream) {
    const float* query = (const float*)d_in[0];
    const float* seg   = (const float*)d_in[1];
    const int*   pos   = (const int*)d_in[2];
    const float* iw1   = (const float*)d_in[3];
    const float* ib1   = (const float*)d_in[4];
    const float* iw2   = (const float*)d_in[5];
    const float* ib2   = (const float*)d_in[6];
    const float* rw1   = (const float*)d_in[7];
    const float* rb1   = (const float*)d_in[8];
    const float* rw2   = (const float*)d_in[9];
    const float* rb2   = (const float*)d_in[10];
    float* out = (float*)d_out;

    char* ws = (char*)d_ws;
    // qhp written by k_mid's qh blocks while seg_red blocks read segp -> keep
    // them in SEPARATE regions (they are live in the same launch).
    float* qhp  = (float*)(ws);                                   // 16 MiB
    float* segp = (float*)(ws + 16 * 1024 * 1024);                // 6.55 MiB
    unsigned char* btI = (unsigned char*)(ws + 23 * 1024 * 1024); // 2 MiB
    float* shwT = (float*)(ws + 25 * 1024 * 1024);                // 51.2 KB
    float* impA = (float*)(ws + 25 * 1024 * 1024 + 64 * 1024);
    float* cA   = (float*)(ws + 25 * 1024 * 1024 + 64 * 1024 + 4096);
    int*   idxA = (int*)  (ws + 25 * 1024 * 1024 + 128 * 1024);   // 160 KB
    float* wnA  = (float*)(ws + 25 * 1024 * 1024 + 320 * 1024);   // 160 KB

    hipLaunchKernelGGL(k_front, dim3(1728), dim3(256), 0, stream,
                       seg, iw1, rw1, segp, btI);
    hipLaunchKernelGGL(k_mid, dim3(612), dim3(256), 0, stream,
                       query, btI, qhp, segp, pos, ib1, iw2, ib2, rb1,
                       shwT, impA, cA);
    hipLaunchKernelGGL(k_rel, dim3(BROWS / 4), dim3(256), 0, stream,
                       qhp, shwT, rw2, rb2, impA, cA, idxA, wnA);
    hipLaunchKernelGGL(k_gather, dim3(BROWS), dim3(256), 0, stream,
                       query, seg, idxA, wnA, out);
}

// Round 12
// 115.199 us; speedup vs baseline: 1.6336x; 1.0011x over previous
//
#include <hip/hip_runtime.h>
#include <math.h>

#define DDIM 4096
#define NSEG 100
#define HDIM 128
#define BROWS 4096
#define TOPK 10
#define KSLICES 8

typedef __attribute__((ext_vector_type(8))) short bf16x8;
typedef __attribute__((ext_vector_type(4))) float f32x4;
typedef __attribute__((ext_vector_type(2))) float f32x2;

// async global->LDS, 16 B per lane; dest = uniform base + lane*16 (HW rule).
__device__ __forceinline__ void gl16(const void* g, void* l) {
    __builtin_amdgcn_global_load_lds(
        (const __attribute__((address_space(1))) unsigned int*)g,
        (__attribute__((address_space(3))) unsigned int*)l,
        16, 0, 0);
}

// Branch-free gelu: A&S 7.1.26 erf (abs err <= 1.5e-7), v_exp_f32 + v_rcp_f32.
__device__ __forceinline__ float gelu_f(float x) {
    float u  = x * 0.70710678118654752440f;
    float au = fminf(fabsf(u), 3.9f);                 // erf(3.9) == 1 to fp32
    float t  = __builtin_amdgcn_rcpf(fmaf(0.3275911f, au, 1.0f));
    float p  = fmaf(fmaf(fmaf(fmaf(1.061405429f, t, -1.453152027f), t,
                              1.421413741f), t, -0.284496736f), t, 0.254829592f) * t;
    float e  = __expf(-au * au);
    float er = fmaf(-p, e, 1.0f);                     // erf(|u|)
    er = copysignf(er, u);
    return 0.5f * x * (1.0f + er);
}

// Packed-pair gelu: identical math per component (VOP3P v_pk_* IEEE == scalar),
// so results are bit-identical to gelu_f on each lane-element.
__device__ __forceinline__ f32x2 gelu2(f32x2 x) {
    f32x2 u  = x * 0.70710678118654752440f;
    f32x2 au = __builtin_elementwise_min(__builtin_elementwise_abs(u), (f32x2)(3.9f));
    f32x2 den = __builtin_elementwise_fma((f32x2)(0.3275911f), au, (f32x2)(1.0f));
    f32x2 t;
    t.x = __builtin_amdgcn_rcpf(den.x);
    t.y = __builtin_amdgcn_rcpf(den.y);
    f32x2 p = __builtin_elementwise_fma(
                __builtin_elementwise_fma(
                  __builtin_elementwise_fma(
                    __builtin_elementwise_fma((f32x2)(1.061405429f), t, (f32x2)(-1.453152027f)),
                    t, (f32x2)(1.421413741f)),
                  t, (f32x2)(-0.284496736f)),
                t, (f32x2)(0.254829592f)) * t;
    f32x2 e;
    e.x = __expf(-au.x * au.x);
    e.y = __expf(-au.y * au.y);
    f32x2 er = __builtin_elementwise_fma(-p, e, (f32x2)(1.0f));
    er.x = copysignf(er.x, u.x);
    er.y = copysignf(er.y, u.y);
    return 0.5f * x * ((f32x2)(1.0f) + er);
}

// Split fp32 -> bf16 hi (truncate) + bf16 lo (exact residual, truncated).
__device__ __forceinline__ void split8(const float4& a, const float4& b,
                                       bf16x8& hi, bf16x8& lo) {
    float v[8] = {a.x, a.y, a.z, a.w, b.x, b.y, b.z, b.w};
    uint hw[4], lw[4];
    #pragma unroll
    for (int j = 0; j < 4; ++j) {
        uint u0 = __float_as_uint(v[2 * j]);
        uint u1 = __float_as_uint(v[2 * j + 1]);
        hw[j] = (u0 >> 16) | (u1 & 0xffff0000u);
        float r0 = v[2 * j]     - __uint_as_float(u0 & 0xffff0000u);
        float r1 = v[2 * j + 1] - __uint_as_float(u1 & 0xffff0000u);
        lw[j] = (__float_as_uint(r0) >> 16) | (__float_as_uint(r1) & 0xffff0000u);
    }
    uint4 h = make_uint4(hw[0], hw[1], hw[2], hw[3]);
    uint4 l = make_uint4(lw[0], lw[1], lw[2], lw[3]);
    hi = __builtin_bit_cast(bf16x8, h);
    lo = __builtin_bit_cast(bf16x8, l);
}

// ---------- K_front: seg_gemm (blocks 0..1599) || bt (blocks 1600..1727) ----------
__global__ void k_front(const float* __restrict__ seg,
                        const float* __restrict__ iw1,
                        const float* __restrict__ rw1,
                        float* __restrict__ segp,
                        unsigned char* __restrict__ btI) {
    __shared__ __align__(16) float shf[32 * 129];   // 16.5 KB, union for both parts
    int bid = blockIdx.x, tid = threadIdx.x;
    if (bid < 1600) {
        float (*segT)[5] = reinterpret_cast<float (*)[5]>(shf);
        int ng = bid % 25;
        int ks = (bid / 25) * 64;
        {
            int k = tid & 63, j = tid >> 6;
            segT[k][j] = seg[(size_t)(ng * 4 + j) * DDIM + ks + k];
        }
        __syncthreads();
        int col = tid;
        float a0 = 0.f, a1 = 0.f, a2 = 0.f, a3 = 0.f;
        const float* w = (col < HDIM) ? (iw1 + col)
                                      : (rw1 + (size_t)DDIM * HDIM + (col - HDIM));
        #pragma unroll 8
        for (int k = 0; k < 64; ++k) {
            float wv = w[(size_t)(ks + k) * HDIM];
            a0 = fmaf(segT[k][0], wv, a0);
            a1 = fmaf(segT[k][1], wv, a1);
            a2 = fmaf(segT[k][2], wv, a2);
            a3 = fmaf(segT[k][3], wv, a3);
        }
        float* outp = segp + (size_t)(bid / 25) * (NSEG * 256) + (size_t)(ng * 4) * 256 + col;
        outp[0] = a0; outp[256] = a1; outp[512] = a2; outp[768] = a3;
    } else {
        float (*tile)[129] = reinterpret_cast<float (*)[129]>(shf);
        int c = bid - 1600;
        #pragma unroll
        for (int i = 0; i < 4; ++i) {
            int e = i * 1024 + tid * 4;
            int k = e >> 7, n = e & 127;
            *reinterpret_cast<float4*>(&tile[k][n]) =
                *reinterpret_cast<const float4*>(rw1 + (size_t)(c * 32 + k) * HDIM + n);
        }
        __syncthreads();
        unsigned char* img = btI + (size_t)c * 16384;
        #pragma unroll
        for (int uu = 0; uu < 2; ++uu) {
            int U = tid * 2 + uu;            // 0..511
            int col = U >> 2;
            int u = U & 3;
            int Z = (col * 64 + u * 16) ^ ((col & 7) << 4);
            uint hw[4], lw[4];
            #pragma unroll
            for (int j = 0; j < 4; ++j) {
                float x0 = tile[u * 8 + 2 * j][col];
                float x1 = tile[u * 8 + 2 * j + 1][col];
                uint u0 = __float_as_uint(x0), u1 = __float_as_uint(x1);
                hw[j] = (u0 >> 16) | (u1 & 0xffff0000u);
                float r0 = x0 - __uint_as_float(u0 & 0xffff0000u);
                float r1 = x1 - __uint_as_float(u1 & 0xffff0000u);
                lw[j] = (__float_as_uint(r0) >> 16) | (__float_as_uint(r1) & 0xffff0000u);
            }
            *reinterpret_cast<uint4*>(img + Z)        = make_uint4(hw[0], hw[1], hw[2], hw[3]);
            *reinterpret_cast<uint4*>(img + 8192 + Z) = make_uint4(lw[0], lw[1], lw[2], lw[3]);
        }
    }
}

// ---------- K_mid: qh_mfma (blocks 0..511) || seg_red (blocks 512..611) ----------
__global__ __launch_bounds__(256)
void k_mid(const float* __restrict__ query,
           const unsigned char* __restrict__ btI,
           float* __restrict__ qhp,
           const float* __restrict__ segp,
           const int* __restrict__ positions,
           const float* __restrict__ ib1,
           const float* __restrict__ iw2,
           const float* __restrict__ ib2,
           const float* __restrict__ rb1,
           float* __restrict__ shwT, float* __restrict__ impA,
           float* __restrict__ cA) {
    __shared__ __align__(16) char lds[49152];       // qh: Ab 16K | Bb 32K; seg_red: red 512B
    int bid = blockIdx.x, tid = threadIdx.x;
    if (bid < 512) {
        float  (*Ab)[2048] = reinterpret_cast<float (*)[2048]>(lds);
        ushort (*Bb)[8192] = reinterpret_cast<ushort (*)[8192]>(lds + 16384);
        int lane = tid & 63, w = tid >> 6;
        int cl = lane & 15, rg = lane >> 4;
        int wm = w >> 1, wn = w & 1;       // wave quadrant: 32 rows x 64 cols
        int m0 = (bid & 63) * 64;
        int ky = bid >> 6;
        int k0 = ky * 512;

        const float* aSrc0;
        const float* aSrc1;
        {
            int X0 = w * 2048 + lane * 16;
            int r0_ = X0 >> 7, kb0 = (X0 & 127) ^ ((r0_ & 7) << 4);
            aSrc0 = query + (size_t)(m0 + r0_) * DDIM + k0 + (kb0 >> 2);
            int X1 = X0 + 1024;
            int r1_ = X1 >> 7, kb1 = (X1 & 127) ^ ((r1_ & 7) << 4);
            aSrc1 = query + (size_t)(m0 + r1_) * DDIM + k0 + (kb1 >> 2);
        }
        const unsigned char* bSrc = btI + (size_t)(ky * 16) * 16384 + w * 4096 + lane * 16;

        f32x4 acc[2][4];
        #pragma unroll
        for (int mi = 0; mi < 2; ++mi)
            #pragma unroll
            for (int nf = 0; nf < 4; ++nf) acc[mi][nf] = (f32x4)0.f;

        {
            char* ad = (char*)&Ab[0][0] + w * 2048;
            char* bd = (char*)&Bb[0][0] + w * 4096;
            gl16(aSrc0, ad);
            gl16(aSrc1, ad + 1024);
            #pragma unroll
            for (int j = 0; j < 4; ++j) gl16(bSrc + j * 1024, bd + j * 1024);
        }
        __syncthreads();

        #pragma unroll 2
        for (int t = 0; t < 16; ++t) {
            int cur = t & 1;
            if (t < 15) {
                char* ad = (char*)&Ab[cur ^ 1][0] + w * 2048;
                char* bd = (char*)&Bb[cur ^ 1][0] + w * 4096;
                gl16(aSrc0 + (t + 1) * 32, ad);
                gl16(aSrc1 + (t + 1) * 32, ad + 1024);
                const unsigned char* bs = bSrc + (size_t)(t + 1) * 16384;
                #pragma unroll
                for (int j = 0; j < 4; ++j) gl16(bs + j * 1024, bd + j * 1024);
            }
            bf16x8 ah[2], al[2];
            #pragma unroll
            for (int mi = 0; mi < 2; ++mi) {
                int row = wm * 32 + mi * 16 + cl;
                int sw = (row & 7) << 4;
                int Sb = row * 128 + rg * 32;
                float4 f0 = *reinterpret_cast<const float4*>((const char*)&Ab[cur][0] + (Sb ^ sw));
                float4 f1 = *reinterpret_cast<const float4*>((const char*)&Ab[cur][0] + ((Sb + 16) ^ sw));
                split8(f0, f1, ah[mi], al[mi]);
            }
            #pragma unroll
            for (int nf = 0; nf < 4; ++nf) {
                int col = wn * 64 + nf * 16 + cl;
                int Z = (col * 64 + rg * 16) ^ ((col & 7) << 4);
                // buffer layout: {hi 0..8191 | lo 8192..16383} BYTES within Bb[cur]
                bf16x8 bh = *reinterpret_cast<const bf16x8*>((const char*)&Bb[cur][0] + Z);
                bf16x8 bl = *reinterpret_cast<const bf16x8*>((const char*)&Bb[cur][0] + 8192 + Z);
                #pragma unroll
                for (int mi = 0; mi < 2; ++mi) {
                    acc[mi][nf] = __builtin_amdgcn_mfma_f32_16x16x32_bf16(ah[mi], bh, acc[mi][nf], 0, 0, 0);
                    acc[mi][nf] = __builtin_amdgcn_mfma_f32_16x16x32_bf16(al[mi], bh, acc[mi][nf], 0, 0, 0);
                    acc[mi][nf] = __builtin_amdgcn_mfma_f32_16x16x32_bf16(ah[mi], bl, acc[mi][nf], 0, 0, 0);
                }
            }
            __syncthreads();
        }

        float* op = qhp + (size_t)ky * (BROWS * HDIM);
        #pragma unroll
        for (int mi = 0; mi < 2; ++mi) {
            int rowb = m0 + wm * 32 + mi * 16 + rg * 4;
            #pragma unroll
            for (int nf = 0; nf < 4; ++nf) {
                int col = wn * 64 + nf * 16 + cl;
                #pragma unroll
                for (int r = 0; r < 4; ++r)
                    op[(size_t)(rowb + r) * HDIM + col] = acc[mi][nf][r];
            }
        }
    } else {
        float* red = reinterpret_cast<float*>(lds);
        int n = bid - 512;
        float v = 0.f;
        #pragma unroll
        for (int s = 0; s < 64; ++s)
            v += segp[(size_t)s * (NSEG * 256) + (size_t)n * 256 + tid];
        if (tid < HDIM) {
            red[tid] = gelu_f(v + ib1[tid]) * iw2[tid];
        } else {
            shwT[(size_t)(tid - HDIM) * NSEG + n] = v + rb1[tid - HDIM];
        }
        __syncthreads();
        if (tid == 0) {
            float s = 0.f;
            for (int j = 0; j < HDIM; ++j) s += red[j];
            float imp = 1.f / (1.f + expf(-(s + ib2[0])));
            float pf = powf(0.95f, (float)NSEG - (float)positions[n] - 1.0f);
            impA[n] = imp;
            cA[n] = imp * (0.5f + 0.5f * pf);
        }
    }
}

// ---------- K4a: rel scores + top-10 -> idxA/wnA ----------
// grid 1024, block 256 (4 waves): wave w owns row b0+w; lane l owns segments
// {2l, 2l+1} (l<50 active). Packed f32x2 gelu: v_pk_* VOP3P halves the
// polynomial issue count; shwT read as one aligned 8-B f32x2; qs[r][h] is a
// wave-uniform LDS broadcast. Per-element math identical to gelu_f.
__global__ __launch_bounds__(256)
void k_rel(const float* __restrict__ qhp,
           const float* __restrict__ shwT,
           const float* __restrict__ rw2,
           const float* __restrict__ rb2,
           const float* __restrict__ impA,
           const float* __restrict__ cA,
           int* __restrict__ idxA,
           float* __restrict__ wnA) {
    __shared__ float qs[4][HDIM];
    __shared__ float scL[4][128], wiL[4][128];
    int tid = threadIdx.x;
    int b0 = blockIdx.x * 4;

    // stage qs: 4 rows x 128 h = 512 sums; thread stages idx = tid, tid+256
    #pragma unroll
    for (int i = 0; i < 2; ++i) {
        int idx = tid + i * 256;
        int r = idx >> 7, h = idx & 127;
        size_t o = (size_t)(b0 + r) * HDIM + h;
        float v = qhp[o];
        #pragma unroll
        for (int s = 1; s < KSLICES; ++s)
            v += qhp[(size_t)s * (BROWS * HDIM) + o];
        qs[r][h] = v;
    }
    __syncthreads();

    int w = tid >> 6, lane = tid & 63;
    int r = w;
    bool act = (lane < 50);
    int n0 = act ? (2 * lane) : 98;         // clamp: inactive lanes read valid mem
    f32x2 acc = (f32x2)(0.f);
    #pragma unroll 2
    for (int h = 0; h < HDIM; ++h) {
        f32x2 s2 = *reinterpret_cast<const f32x2*>(&shwT[h * NSEG + n0]);
        float q = qs[r][h];                 // wave-uniform -> LDS broadcast
        float wh = rw2[h];                  // wave-uniform -> scalar load
        f32x2 x2 = q + s2;
        acc = __builtin_elementwise_fma(gelu2(x2), (f32x2)(wh), acc);
    }
    if (act) {
        float rb2f = rb2[0];
        float rel0 = 1.f / (1.f + expf(-(acc.x + rb2f)));
        float rel1 = 1.f / (1.f + expf(-(acc.y + rb2f)));
        scL[r][n0]     = cA[n0] * rel0;      wiL[r][n0]     = impA[n0] * rel0;
        scL[r][n0 + 1] = cA[n0 + 1] * rel1;  wiL[r][n0 + 1] = impA[n0 + 1] * rel1;
    }
    __syncthreads();

    // top-k: wave w -> row w (register-only butterfly, proven r8 form)
    {
        int rr = w;
        float s1 = scL[rr][lane];
        float w1 = wiL[rr][lane];
        int i2 = lane + 64;
        float s2 = (i2 < NSEG) ? scL[rr][i2] : -1e30f;
        float w2 = (i2 < NSEG) ? wiL[rr][i2] : 0.f;

        float wv[TOPK]; int idxv[TOPK]; float wsum = 0.f;
        #pragma unroll
        for (int k = 0; k < TOPK; ++k) {
            float s; int i;
            if (s2 > s1) { s = s2; i = i2; } else { s = s1; i = lane; }
            #pragma unroll
            for (int off = 1; off < 64; off <<= 1) {
                float os = __shfl_xor(s, off);
                int oi = __shfl_xor(i, off);
                if (os > s || (os == s && oi < i)) { s = os; i = oi; }
            }
            float wi = __shfl((i < 64) ? w1 : w2, i & 63);
            idxv[k] = i; wv[k] = wi; wsum += wi;
            if (i == lane) s1 = -1e30f;
            if (i == i2)   s2 = -1e30f;
        }
        if (lane == 0) {
            int b = b0 + rr;
            float denom = wsum + 1e-8f;
            #pragma unroll
            for (int k = 0; k < TOPK; ++k) {
                idxA[b * TOPK + k] = idxv[k];
                wnA[b * TOPK + k]  = wv[k] / denom;
            }
        }
    }
}

// ---------- K4c: pure streaming gather: out = query + sum wn[k]*seg[idx[k]] ----------
// grid 4096, block 256. Weights/pointers via wave-uniform scalar loads; no LDS/barriers.
__global__ void k_gather(const float* __restrict__ query,
                         const float* __restrict__ seg,
                         const int* __restrict__ idxA,
                         const float* __restrict__ wnA,
                         float* __restrict__ out) {
    int b = blockIdx.x, tid = threadIdx.x;
    const int*   ip = idxA + b * TOPK;
    const float* wp = wnA  + b * TOPK;
    float wn[TOPK]; const float* srow[TOPK];
    #pragma unroll
    for (int k = 0; k < TOPK; ++k) {
        wn[k]   = wp[k];                          // uniform -> s_load
        srow[k] = seg + (size_t)ip[k] * DDIM;     // uniform -> s_load + sgpr addr
    }
    const float* qrow = query + (size_t)b * DDIM;
    float* orow = out + (size_t)b * DDIM;

    float4 q[4];
    #pragma unroll
    for (int c = 0; c < 4; ++c)
        q[c] = *reinterpret_cast<const float4*>(qrow + c * 1024 + tid * 4);
    #pragma unroll
    for (int k = 0; k < TOPK; ++k) {
        float4 s[4];
        #pragma unroll
        for (int c = 0; c < 4; ++c)
            s[c] = *reinterpret_cast<const float4*>(srow[k] + c * 1024 + tid * 4);
        #pragma unroll
        for (int c = 0; c < 4; ++c) {
            q[c].x = fmaf(wn[k], s[c].x, q[c].x);
            q[c].y = fmaf(wn[k], s[c].y, q[c].y);
            q[c].z = fmaf(wn[k], s[c].z, q[c].z);
            q[c].w = fmaf(wn[k], s[c].w, q[c].w);
        }
    }
    #pragma unroll
    for (int c = 0; c < 4; ++c)
        *reinterpret_cast<float4*>(orow + c * 1024 + tid * 4) = q[c];
}

extern "C" void kernel_launch(void* const* d_in, const int* in_sizes, int n_in,
                              void* d_out, int out_size, void* d_ws, size_t ws_size,
                              hipStream_t stream) {
    const float* query = (const float*)d_in[0];
    const float* seg   = (const float*)d_in[1];
    const int*   pos   = (const int*)d_in[2];
    const float* iw1   = (const float*)d_in[3];
    const float* ib1   = (const float*)d_in[4];
    const float* iw2   = (const float*)d_in[5];
    const float* ib2   = (const float*)d_in[6];
    const float* rw1   = (const float*)d_in[7];
    const float* rb1   = (const float*)d_in[8];
    const float* rw2   = (const float*)d_in[9];
    const float* rb2   = (const float*)d_in[10];
    float* out = (float*)d_out;

    char* ws = (char*)d_ws;
    // qhp written by k_mid's qh blocks while seg_red blocks read segp -> keep
    // them in SEPARATE regions (they are live in the same launch).
    float* qhp  = (float*)(ws);                                   // 16 MiB
    float* segp = (float*)(ws + 16 * 1024 * 1024);                // 6.55 MiB
    unsigned char* btI = (unsigned char*)(ws + 23 * 1024 * 1024); // 2 MiB
    float* shwT = (float*)(ws + 25 * 1024 * 1024);                // 51.2 KB
    float* impA = (float*)(ws + 25 * 1024 * 1024 + 64 * 1024);
    float* cA   = (float*)(ws + 25 * 1024 * 1024 + 64 * 1024 + 4096);
    int*   idxA = (int*)  (ws + 25 * 1024 * 1024 + 128 * 1024);   // 160 KB
    float* wnA  = (float*)(ws + 25 * 1024 * 1024 + 320 * 1024);   // 160 KB

    hipLaunchKernelGGL(k_front, dim3(1728), dim3(256), 0, stream,
                       seg, iw1, rw1, segp, btI);
    hipLaunchKernelGGL(k_mid, dim3(612), dim3(256), 0, stream,
                       query, btI, qhp, segp, pos, ib1, iw2, ib2, rb1,
                       shwT, impA, cA);
    hipLaunchKernelGGL(k_rel, dim3(BROWS / 4), dim3(256), 0, stream,
                       qhp, shwT, rw2, rb2, impA, cA, idxA, wnA);
    hipLaunchKernelGGL(k_gather, dim3(BROWS), dim3(256), 0, stream,
                       query, seg, idxA, wnA, out);
}